// Round 12
// baseline (644.751 us; speedup 1.0000x reference)
//
#include <hip/hip_runtime.h>
#include <hip/hip_bf16.h>
#include <math.h>

// Problem constants
#define B_ 32
#define S_ 64
#define MV_ 30
#define V_ 20000
#define E_ 256
#define H_ 512
#define L_ 128
#define H3_ 1536
#define BS_ 2048   // B*S
#define NB4 256    // k4 grid blocks (persistent, co-resident; 8 groups x 32)
#define NEG7 -3.0e38f
#define SENT 0xFFF8000000000000ULL   // quiet NaN; h is always finite -> unreachable

typedef __attribute__((ext_vector_type(8))) short short8v;  // 8 bf16 (4 VGPRs)
typedef __attribute__((ext_vector_type(4))) float f32x4;
typedef unsigned long long ull_;

// ---------------------------------------------------------------------------
// K12: blocks [0,2048): k1 multi-hot embed body (verbatim);
//      blocks [2048,2112): k2 h0 body (grouped packing, step-0 buffer);
//      blocks [2112,3120): NaN-sentinel init of step buffers 1..63 (8.25MB).
// hstep layout: hstep[s*16384 + g*2048 + u*4 + b_in_group], s = 0..63
// ---------------------------------------------------------------------------
__global__ __launch_bounds__(256) void k12(const int* __restrict__ seq,
                                           const float* __restrict__ Ew,
                                           const float* __restrict__ z,
                                           const float* __restrict__ Wl,
                                           const float* __restrict__ bl,
                                           double* __restrict__ emb,
                                           double* __restrict__ hstep) {
    __shared__ int sidx[MV_];
    int bid = blockIdx.x;
    int t = threadIdx.x;
    if (bid < BS_) {
        int row = bid;
        if (t < MV_) sidx[t] = seq[row * MV_ + t];
        __syncthreads();
        double acc = 0.0;
        for (int i = 0; i < MV_; ++i) {
            int id = sidx[i];
            if (id == 0) continue;
            bool dup = false;
            for (int q = 0; q < i; ++q) dup = dup || (sidx[q] == id);
            if (!dup) acc += (double)Ew[(size_t)id * E_ + t];
        }
        emb[(size_t)row * E_ + t] = tanh(acc);
    } else if (bid < BS_ + 64) {
        int o = (bid - BS_) * 256 + t;   // < 16384
        int b = o >> 9;
        int j = o & 511;
        const float4* zr = (const float4*)(z + (size_t)b * L_);
        const float4* wr = (const float4*)(Wl + (size_t)j * L_);
        double acc = (double)bl[j];
#pragma unroll
        for (int k = 0; k < L_ / 4; ++k) {
            float4 a = zr[k];
            float4 w = wr[k];
            acc += (double)a.x * (double)w.x + (double)a.y * (double)w.y
                 + (double)a.z * (double)w.z + (double)a.w * (double)w.w;
        }
        hstep[(size_t)(b >> 2) * 2048 + j * 4 + (b & 3)] = acc;
    } else {
        // sentinel fill for steps 1..63: 63*16384 = 1,032,192 ulls
        ull_* hs = (ull_*)hstep;
        size_t i = (size_t)(bid - (BS_ + 64)) * 1024 + (size_t)t * 4;
        hs[16384 + i + 0] = SENT;
        hs[16384 + i + 1] = SENT;
        hs[16384 + i + 2] = SENT;
        hs[16384 + i + 3] = SENT;
    }
}

// ---------------------------------------------------------------------------
// K3: Gi = emb @ W_ih^T + b_ih  (2048x1536, K=256), f64. 64x64 tile, 4x4/thread.
//     Output PACKED for k4: gi_p[(((s*512 + unit)*3 + gate)*32 + b)]
// ---------------------------------------------------------------------------
__global__ __launch_bounds__(256) void k3_gi(const double* __restrict__ A,
                                             const float* __restrict__ Bm,
                                             const float* __restrict__ bih,
                                             double* __restrict__ gi) {
    __shared__ double As[16][66];
    __shared__ double Bs[16][66];
    int t = threadIdx.x;
    int n0 = blockIdx.x * 64;   // 24
    int m0 = blockIdx.y * 64;   // 32
    int tx = t & 15, ty = t >> 4;
    int ml = t >> 2;
    int kl = (t & 3) * 4;
    double acc[4][4];
#pragma unroll
    for (int i = 0; i < 4; ++i)
#pragma unroll
        for (int j = 0; j < 4; ++j) acc[i][j] = 0.0;

    for (int kt = 0; kt < 256; kt += 16) {
        double4 av = *(const double4*)(A + (size_t)(m0 + ml) * 256 + kt + kl);
        float4 bv = *(const float4*)(Bm + (size_t)(n0 + ml) * 256 + kt + kl);
        As[kl + 0][ml] = av.x; As[kl + 1][ml] = av.y; As[kl + 2][ml] = av.z; As[kl + 3][ml] = av.w;
        Bs[kl + 0][ml] = (double)bv.x; Bs[kl + 1][ml] = (double)bv.y;
        Bs[kl + 2][ml] = (double)bv.z; Bs[kl + 3][ml] = (double)bv.w;
        __syncthreads();
#pragma unroll
        for (int kk = 0; kk < 16; ++kk) {
            double2 a01 = *(const double2*)&As[kk][ty * 4];
            double2 a23 = *(const double2*)&As[kk][ty * 4 + 2];
            double2 b01 = *(const double2*)&Bs[kk][tx * 4];
            double2 b23 = *(const double2*)&Bs[kk][tx * 4 + 2];
            double am[4] = {a01.x, a01.y, a23.x, a23.y};
            double bn[4] = {b01.x, b01.y, b23.x, b23.y};
#pragma unroll
            for (int i = 0; i < 4; ++i)
#pragma unroll
                for (int j = 0; j < 4; ++j) acc[i][j] += am[i] * bn[j];
        }
        __syncthreads();
    }
#pragma unroll
    for (int i = 0; i < 4; ++i) {
        int m = m0 + ty * 4 + i;
        int bb = m >> 6, ss = m & 63;
#pragma unroll
        for (int j = 0; j < 4; ++j) {
            int n = n0 + tx * 4 + j;
            int g = n >> 9, u = n & 511;
            gi[(((size_t)(ss * 512 + u)) * 3 + g) * 32 + bb] = acc[i][j] + (double)bih[n];
        }
    }
}

// ---------------------------------------------------------------------------
// K4 (round-16, PROVEN 265us): sentinel data-poll + two-phase chunked overlap.
// ---------------------------------------------------------------------------
__global__ __launch_bounds__(256, 1) void k4_gru(const double* __restrict__ gi,
                                                 const float* __restrict__ whh,
                                                 const float* __restrict__ bhh,
                                                 const int* __restrict__ length,
                                                 double* __restrict__ hstep,
                                                 float* __restrict__ outs,
                                                 short* __restrict__ A16) {
    __shared__ double hl[2112];               // group h: idx = e + (e>>7)*4
    __shared__ double part[2][4][16][13];     // [parity][wave][ul][gate*4+b], pad 13

    int t = threadIdx.x;
    int wv = t >> 6;
    int lane = t & 63;
    int bid = blockIdx.x;
    int g = bid & 7;          // group
    int beta = bid >> 3;      // block-in-group 0..31

    // matvec lane mapping: (ul, ks); wave wv covers k in [wv*128, wv*128+128)
    int ul = lane >> 2, ks = lane & 3;

    // ---- W_hh slice into registers: rows (gate*512 + beta*16 + ul),
    //      cols [wv*128 + ks*32, +32) = 8 float4 per gate ----
    const float* wbase = whh + ((size_t)(beta * 16 + ul)) * 512 + wv * 128 + ks * 32;
    float4 w0r[8], w1r[8], w2r[8];
#pragma unroll
    for (int c = 0; c < 8; ++c) {
        w0r[c] = *(const float4*)(wbase + c * 4);
        w1r[c] = *(const float4*)(wbase + 512 * 512 + c * 4);
        w2r[c] = *(const float4*)(wbase + 1024 * 512 + c * 4);
    }

    // ---- initial h (step 0), group-local 16KB (plain loads; pre-k4 data) ----
    const double* hg0 = hstep + (size_t)g * 2048;
    {
#pragma unroll
        for (int j = 0; j < 8; ++j) {
            int e = t + j * 256;
            hl[e + ((e >> 7) << 2)] = hg0[e];
        }
    }
    __syncthreads();

    // wave0 per-lane elementwise state: lane = (u2 0..15, b2 0..3)
    int u2 = lane >> 2, b2 = lane & 3;
    int u_g = beta * 16 + u2;      // global unit
    int b_g = g * 4 + b2;          // global batch
    double gr = 0.0, gz = 0.0, gn = 0.0, bhr_ = 0.0, bhz_ = 0.0, bhn_ = 0.0;
    double hv = 0.0;               // own h_prev in register
    int len = 0;
    if (wv == 0) {
        bhr_ = (double)bhh[u_g];
        bhz_ = (double)bhh[u_g + 512];
        bhn_ = (double)bhh[u_g + 1024];
        len = length[b_g];
        hv = hg0[u_g * 4 + b2];
        size_t gb = ((size_t)u_g * 3) * 32 + b_g;
        gr = gi[gb]; gz = gi[gb + 32]; gn = gi[gb + 64];
    }

    const double* hr = &hl[(wv * 128 + ks * 32) * 4 + ((wv * 4 + ks) << 2)];

    for (int s = 0; s < S_; ++s) {
        int par = s & 1;
        ull_ ta[4], tb[4];
        const ull_* src = (const ull_*)(hstep + (size_t)s * 16384 + (size_t)g * 2048)
                          + wv * 512;
        if (s > 0) {
            // ---- phase A: poll even-j chunks (coalesced lane-major) ----
            while (true) {
                bool ok = true;
#pragma unroll
                for (int j = 0; j < 4; ++j) {
                    ta[j] = __hip_atomic_load(&src[(2 * j) * 64 + lane],
                                              __ATOMIC_RELAXED, __HIP_MEMORY_SCOPE_AGENT);
                    ok = ok && (ta[j] != SENT);
                }
                if (__all(ok)) break;
                __builtin_amdgcn_s_sleep(1);
            }
            // first-try odd-j loads: in flight during stage + matvec A
#pragma unroll
            for (int j = 0; j < 4; ++j)
                tb[j] = __hip_atomic_load(&src[(2 * j + 1) * 64 + lane],
                                          __ATOMIC_RELAXED, __HIP_MEMORY_SCOPE_AGENT);
            asm volatile("" ::: "memory");
            {
                ull_* hlu = (ull_*)hl;
#pragma unroll
                for (int j = 0; j < 4; ++j) {
                    int e = wv * 512 + (2 * j) * 64 + lane;
                    hlu[e + ((e >> 7) << 2)] = ta[j];
                }
            }
        }

        double a0[4] = {0, 0, 0, 0}, a1[4] = {0, 0, 0, 0}, a2[4] = {0, 0, 0, 0};
        // ---- matvec phase A: c = 0..3 (k_local in even-j chunks) ----
#pragma unroll
        for (int c = 0; c < 4; ++c) {
            const double* hp = hr + c * 16;
            double2 hA0 = *(const double2*)(hp + 0),  hB0 = *(const double2*)(hp + 2);
            double2 hA1 = *(const double2*)(hp + 4),  hB1 = *(const double2*)(hp + 6);
            double2 hA2 = *(const double2*)(hp + 8),  hB2 = *(const double2*)(hp + 10);
            double2 hA3 = *(const double2*)(hp + 12), hB3 = *(const double2*)(hp + 14);
            float4 w0 = w0r[c], w1 = w1r[c], w2 = w2r[c];
            { double d0 = (double)w0.x, d1 = (double)w1.x, d2 = (double)w2.x;
              a0[0] += hA0.x * d0; a0[1] += hA0.y * d0; a0[2] += hB0.x * d0; a0[3] += hB0.y * d0;
              a1[0] += hA0.x * d1; a1[1] += hA0.y * d1; a1[2] += hB0.x * d1; a1[3] += hB0.y * d1;
              a2[0] += hA0.x * d2; a2[1] += hA0.y * d2; a2[2] += hB0.x * d2; a2[3] += hB0.y * d2; }
            { double d0 = (double)w0.y, d1 = (double)w1.y, d2 = (double)w2.y;
              a0[0] += hA1.x * d0; a0[1] += hA1.y * d0; a0[2] += hB1.x * d0; a0[3] += hB1.y * d0;
              a1[0] += hA1.x * d1; a1[1] += hA1.y * d1; a1[2] += hB1.x * d1; a1[3] += hB1.y * d1;
              a2[0] += hA1.x * d2; a2[1] += hA1.y * d2; a2[2] += hB1.x * d2; a2[3] += hB1.y * d2; }
            { double d0 = (double)w0.z, d1 = (double)w1.z, d2 = (double)w2.z;
              a0[0] += hA2.x * d0; a0[1] += hA2.y * d0; a0[2] += hB2.x * d0; a0[3] += hB2.y * d0;
              a1[0] += hA2.x * d1; a1[1] += hA2.y * d1; a1[2] += hB2.x * d1; a1[3] += hB2.y * d1;
              a2[0] += hA2.x * d2; a2[1] += hA2.y * d2; a2[2] += hB2.x * d2; a2[3] += hB2.y * d2; }
            { double d0 = (double)w0.w, d1 = (double)w1.w, d2 = (double)w2.w;
              a0[0] += hA3.x * d0; a0[1] += hA3.y * d0; a0[2] += hB3.x * d0; a0[3] += hB3.y * d0;
              a1[0] += hA3.x * d1; a1[1] += hA3.y * d1; a1[2] += hB3.x * d1; a1[3] += hB3.y * d1;
              a2[0] += hA3.x * d2; a2[1] += hA3.y * d2; a2[2] += hB3.x * d2; a2[3] += hB3.y * d2; }
        }

        if (s > 0) {
            // ---- phase B: verify/complete odd-j chunks, stage ----
            while (true) {
                bool ok = true;
#pragma unroll
                for (int j = 0; j < 4; ++j) ok = ok && (tb[j] != SENT);
                if (__all(ok)) break;
                __builtin_amdgcn_s_sleep(1);
#pragma unroll
                for (int j = 0; j < 4; ++j)
                    tb[j] = __hip_atomic_load(&src[(2 * j + 1) * 64 + lane],
                                              __ATOMIC_RELAXED, __HIP_MEMORY_SCOPE_AGENT);
            }
            asm volatile("" ::: "memory");
            {
                ull_* hlu = (ull_*)hl;
#pragma unroll
                for (int j = 0; j < 4; ++j) {
                    int e = wv * 512 + (2 * j + 1) * 64 + lane;
                    hlu[e + ((e >> 7) << 2)] = tb[j];
                }
            }
        }

        // ---- matvec phase B: c = 4..7 (k_local in odd-j chunks) ----
#pragma unroll
        for (int c = 4; c < 8; ++c) {
            const double* hp = hr + c * 16;
            double2 hA0 = *(const double2*)(hp + 0),  hB0 = *(const double2*)(hp + 2);
            double2 hA1 = *(const double2*)(hp + 4),  hB1 = *(const double2*)(hp + 6);
            double2 hA2 = *(const double2*)(hp + 8),  hB2 = *(const double2*)(hp + 10);
            double2 hA3 = *(const double2*)(hp + 12), hB3 = *(const double2*)(hp + 14);
            float4 w0 = w0r[c], w1 = w1r[c], w2 = w2r[c];
            { double d0 = (double)w0.x, d1 = (double)w1.x, d2 = (double)w2.x;
              a0[0] += hA0.x * d0; a0[1] += hA0.y * d0; a0[2] += hB0.x * d0; a0[3] += hB0.y * d0;
              a1[0] += hA0.x * d1; a1[1] += hA0.y * d1; a1[2] += hB0.x * d1; a1[3] += hB0.y * d1;
              a2[0] += hA0.x * d2; a2[1] += hA0.y * d2; a2[2] += hB0.x * d2; a2[3] += hB0.y * d2; }
            { double d0 = (double)w0.y, d1 = (double)w1.y, d2 = (double)w2.y;
              a0[0] += hA1.x * d0; a0[1] += hA1.y * d0; a0[2] += hB1.x * d0; a0[3] += hB1.y * d0;
              a1[0] += hA1.x * d1; a1[1] += hA1.y * d1; a1[2] += hB1.x * d1; a1[3] += hB1.y * d1;
              a2[0] += hA1.x * d2; a2[1] += hA1.y * d2; a2[2] += hB1.x * d2; a2[3] += hB1.y * d2; }
            { double d0 = (double)w0.z, d1 = (double)w1.z, d2 = (double)w2.z;
              a0[0] += hA2.x * d0; a0[1] += hA2.y * d0; a0[2] += hB2.x * d0; a0[3] += hB2.y * d0;
              a1[0] += hA2.x * d1; a1[1] += hA2.y * d1; a1[2] += hB2.x * d1; a1[3] += hB2.y * d1;
              a2[0] += hA2.x * d2; a2[1] += hA2.y * d2; a2[2] += hB2.x * d2; a2[3] += hB2.y * d2; }
            { double d0 = (double)w0.w, d1 = (double)w1.w, d2 = (double)w2.w;
              a0[0] += hA3.x * d0; a0[1] += hA3.y * d0; a0[2] += hB3.x * d0; a0[3] += hB3.y * d0;
              a1[0] += hA3.x * d1; a1[1] += hA3.y * d1; a1[2] += hB3.x * d1; a1[3] += hB3.y * d1;
              a2[0] += hA3.x * d2; a2[1] += hA3.y * d2; a2[2] += hB3.x * d2; a2[3] += hB3.y * d2; }
        }

        // reduce over ks (lanes xor 1, 2)
#pragma unroll
        for (int b = 0; b < 4; ++b) {
            a0[b] += __shfl_xor(a0[b], 1); a0[b] += __shfl_xor(a0[b], 2);
            a1[b] += __shfl_xor(a1[b], 1); a1[b] += __shfl_xor(a1[b], 2);
            a2[b] += __shfl_xor(a2[b], 1); a2[b] += __shfl_xor(a2[b], 2);
        }
        if (ks == 0) {
#pragma unroll
            for (int b = 0; b < 4; ++b) {
                part[par][wv][ul][0 * 4 + b] = a0[b];
                part[par][wv][ul][1 * 4 + b] = a1[b];
                part[par][wv][ul][2 * 4 + b] = a2[b];
            }
        }
        __syncthreads();   // S1 (only barrier per step): partials visible

        if (wv == 0) {
            double s0 = part[par][0][u2][0 * 4 + b2] + part[par][1][u2][0 * 4 + b2]
                      + part[par][2][u2][0 * 4 + b2] + part[par][3][u2][0 * 4 + b2];
            double s1 = part[par][0][u2][1 * 4 + b2] + part[par][1][u2][1 * 4 + b2]
                      + part[par][2][u2][1 * 4 + b2] + part[par][3][u2][1 * 4 + b2];
            double s2 = part[par][0][u2][2 * 4 + b2] + part[par][1][u2][2 * 4 + b2]
                      + part[par][2][u2][2 * 4 + b2] + part[par][3][u2][2 * 4 + b2];
            double r  = 1.0 / (1.0 + exp(-(gr + s0 + bhr_)));
            double zt = 1.0 / (1.0 + exp(-(gz + s1 + bhz_)));
            double n  = tanh(gn + r * (s2 + bhn_));
            double hn_ = (1.0 - zt) * n + zt * hv;
            hv = hn_;
            if (s < S_ - 1) {
                // publish to write-once step buffer; the data IS the flag
                ull_* hdst = (ull_*)(hstep + (size_t)(s + 1) * 16384 + (size_t)g * 2048);
                // (beta*16+u2)*4 + b2 == beta*64 + lane -> fully coalesced 512B store
                __hip_atomic_store(&hdst[beta * 64 + lane],
                                   __builtin_bit_cast(ull_, hn_),
                                   __ATOMIC_RELAXED, __HIP_MEMORY_SCOPE_AGENT);
                // gi prefetch for s+1 (overlaps consumers' polls)
                size_t gb = ((size_t)((s + 1) * 512 + u_g) * 3) * 32 + b_g;
                gr = gi[gb]; gz = gi[gb + 32]; gn = gi[gb + 64];
            }
            float ov = (s < len) ? (float)hn_ : 0.0f;
            size_t oidx = (size_t)(b_g * 64 + s) * H_ + u_g;
            outs[oidx] = ov;
            {   // fused bf16 conversion (was k_prep2's A-half)
                unsigned u = __builtin_bit_cast(unsigned, ov);
                A16[oidx] = (short)((u + 0x7FFFu + ((u >> 16) & 1u)) >> 16);
            }
        }
    }
}

// ---------------------------------------------------------------------------
// bf16 helpers + prep kernel (W16 only): blocks [0,5000) convert W_out.
// ---------------------------------------------------------------------------
__device__ __forceinline__ unsigned short f2b_(float x) {
    unsigned u = __builtin_bit_cast(unsigned, x);
    return (unsigned short)((u + 0x7FFFu + ((u >> 16) & 1u)) >> 16);   // RNE
}
__device__ __forceinline__ short8v pack8_(float4 a, float4 b) {
    short8v r;
    r[0] = (short)f2b_(a.x); r[1] = (short)f2b_(a.y);
    r[2] = (short)f2b_(a.z); r[3] = (short)f2b_(a.w);
    r[4] = (short)f2b_(b.x); r[5] = (short)f2b_(b.y);
    r[6] = (short)f2b_(b.z); r[7] = (short)f2b_(b.w);
    return r;
}
__global__ __launch_bounds__(256) void k_prep2(const float* __restrict__ Wsrc,
                                               short* __restrict__ W16) {
    int i = blockIdx.x * 256 + threadIdx.x;  // < 1,280,000
    float4 a = *(const float4*)&Wsrc[(size_t)i * 8];
    float4 b = *(const float4*)&Wsrc[(size_t)i * 8 + 4];
    *(short8v*)&W16[(size_t)i * 8] = pack8_(a, b);
}

// ---------------------------------------------------------------------------
// K5 (round-21 = round-17 retile, passed R17/R18): p = sigmoid(A16 @ W16^T
//   + b_out), bf16 MFMA, BK=64. 128x256 block; 4 waves each own 64x128
//   (acc 4x8). ds_reads per MFMA 0.50 -> 0.375; B-staging 1 thread/row
//   (8 short8v per thread). LDK5=72 bank profile and fragment math
//   unchanged. Grid 1264 = 16 m-tiles x 79 n-tiles (bijective 8x158 XCD
//   swizzle). LDS 55.3KB -> 2 blocks/CU.
// ---------------------------------------------------------------------------
#define LDK5 72
__global__ __launch_bounds__(256, 2) void k5_mfma(const short* __restrict__ A16,  // 2048x512 bf16
                                                  const short* __restrict__ W16,  // 20000x512 bf16
                                                  const float* __restrict__ bo,
                                                  float* __restrict__ pOut) {
    __shared__ short As[128 * LDK5];   // 18.4KB
    __shared__ short Bs[256 * LDK5];   // 36.9KB
    int t = threadIdx.x;
    int bid = blockIdx.x;                       // 0..1263
    int swz = (bid & 7) * 158 + (bid >> 3);     // XCD swizzle (bijective, 1264=8*158)
    int m0 = (swz & 15) * 128;                  // 16 m-tiles
    int n0 = (swz >> 4) * 256;                  // 79 n-tiles
    int lane = t & 63, wv = t >> 6;
    int wr = wv >> 1, wc = wv & 1;              // wave -> 64-row x 128-col quadrant
    int ml = t >> 1;                            // 0..127 (A staging row)
    int kl = (t & 1) * 32;                      // 0 or 32 (A staging k-offset)

    const short* Arow = A16 + (size_t)(m0 + ml) * H_ + kl;
    int vrow = n0 + t;                          // B staging: 1 thread per row
    bool vok = vrow < V_;
    const short* Wrow = W16 + (size_t)(vok ? vrow : 0) * H_;
    short8v zz = (short8v){0, 0, 0, 0, 0, 0, 0, 0};

    f32x4 acc[4][8];
#pragma unroll
    for (int i = 0; i < 4; ++i)
#pragma unroll
        for (int j = 0; j < 8; ++j) acc[i][j] = (f32x4){0.f, 0.f, 0.f, 0.f};

    int ko = lane >> 4;       // 0..3 (k-group of 8)
    int rr = lane & 15;       // fragment row/col

    for (int kt = 0; kt < H_; kt += 64) {
        short8v a0 = *(const short8v*)(Arow + kt);
        short8v a1 = *(const short8v*)(Arow + kt + 8);
        short8v a2 = *(const short8v*)(Arow + kt + 16);
        short8v a3 = *(const short8v*)(Arow + kt + 24);
        short8v bb[8];
#pragma unroll
        for (int jj = 0; jj < 8; ++jj)
            bb[jj] = vok ? *(const short8v*)(Wrow + kt + jj * 8) : zz;
        *(short8v*)&As[ml * LDK5 + kl]      = a0;
        *(short8v*)&As[ml * LDK5 + kl + 8]  = a1;
        *(short8v*)&As[ml * LDK5 + kl + 16] = a2;
        *(short8v*)&As[ml * LDK5 + kl + 24] = a3;
#pragma unroll
        for (int jj = 0; jj < 8; ++jj)
            *(short8v*)&Bs[t * LDK5 + jj * 8] = bb[jj];
        __syncthreads();

#pragma unroll
        for (int kh = 0; kh < 2; ++kh) {
            short8v af[4], bf[8];
#pragma unroll
            for (int i = 0; i < 4; ++i)
                af[i] = *(const short8v*)&As[(wr * 64 + i * 16 + rr) * LDK5 + kh * 32 + ko * 8];
#pragma unroll
            for (int j = 0; j < 8; ++j)
                bf[j] = *(const short8v*)&Bs[(wc * 128 + j * 16 + rr) * LDK5 + kh * 32 + ko * 8];
#pragma unroll
            for (int i = 0; i < 4; ++i)
#pragma unroll
                for (int j = 0; j < 8; ++j)
                    acc[i][j] = __builtin_amdgcn_mfma_f32_16x16x32_bf16(af[i], bf[j], acc[i][j], 0, 0, 0);
        }
        __syncthreads();
    }

    int cr4 = (lane >> 4) * 4;
    float bov[8];
#pragma unroll
    for (int j = 0; j < 8; ++j) {
        int v = n0 + wc * 128 + j * 16 + rr;
        bov[j] = (v < V_) ? bo[v] : 0.f;
    }
#pragma unroll
    for (int i = 0; i < 4; ++i) {
#pragma unroll
        for (int j = 0; j < 8; ++j) {
            int v = n0 + wc * 128 + j * 16 + rr;
            if (v < V_) {
#pragma unroll
                for (int r = 0; r < 4; ++r) {
                    int m = m0 + wr * 64 + i * 16 + cr4 + r;
                    float x = acc[i][j][r] + bov[j];
                    pOut[(size_t)m * V_ + v] = 1.0f / (1.0f + expf(-x));
                }
            }
        }
    }
}

// ---------------------------------------------------------------------------
// K7a (round-20 PROVEN): per-wave top-32, sorted-top-4 maintenance.
// ---------------------------------------------------------------------------
__global__ __launch_bounds__(512) void k7a_cand(const float* __restrict__ pOut,
                                                float* __restrict__ candV,
                                                int* __restrict__ candI) {
    int row = blockIdx.x;
    int t = threadIdx.x;
    int wv = t >> 6;          // chunk 0..7 (2500 cols each)
    int lane = t & 63;
    const float* rowp = pOut + (size_t)row * V_ + wv * 2500;

    float rv[40];
#pragma unroll
    for (int q4 = 0; q4 < 10; ++q4) {
        int base = q4 * 256 + lane * 4;
        float4 v4 = *(const float4*)(rowp + base);   // tails stay inside d_out; masked below
        float vv[4] = {v4.x, v4.y, v4.z, v4.w};
#pragma unroll
        for (int c = 0; c < 4; ++c) {
            int li = base + c;
            int col = wv * 2500 + li;
            bool ok = (li < 2500) && (col >= 3);
            rv[q4 * 4 + c] = ok ? vv[c] : NEG7;
        }
    }

    // sorted top-4 (v desc, q asc): stable strict-> insertion in q order
    float v0 = NEG7, v1 = NEG7, v2 = NEG7, v3 = NEG7;
    int   i0 = 0,    i1 = 0,    i2 = 0,    i3 = 0;
#pragma unroll
    for (int q = 0; q < 40; ++q) {
        float v = rv[q];
        if (v > v3) {
            if (v > v1) {
                if (v > v0) { v3 = v2; i3 = i2; v2 = v1; i2 = i1; v1 = v0; i1 = i0; v0 = v; i0 = q; }
                else        { v3 = v2; i3 = i2; v2 = v1; i2 = i1; v1 = v; i1 = q; }
            } else {
                if (v > v2) { v3 = v2; i3 = i2; v2 = v; i2 = q; }
                else        { v3 = v; i3 = q; }
            }
        }
    }

    ull_ used = 0;
    int pops = 0;
    int myidx = wv * 2500 + (i0 >> 2) * 256 + lane * 4 + (i0 & 3);

    float keepv = NEG7; int keepi = 0;
#pragma unroll 1
    for (int r = 0; r < 32; ++r) {
        float bv = v0; int bi = myidx;
#pragma unroll
        for (int m = 1; m < 64; m <<= 1) {
            float ov = __shfl_xor(bv, m);
            int   oi = __shfl_xor(bi, m);
            if (ov > bv || (ov == bv && oi < bi)) { bv = ov; bi = oi; }
        }
        if (lane == r) { keepv = bv; keepi = bi; }
        if (myidx == bi) {           // this lane won (idx unique -> exactly one)
            used |= (1ull << i0);
            v0 = v1; i0 = i1; v1 = v2; i1 = i2; v2 = v3; i2 = i3; v3 = NEG7; i3 = 0;
            if (++pops == 4) {       // list exhausted: rare rebuild (excl. used)
                pops = 0;
                v0 = v1 = v2 = v3 = NEG7; i0 = i1 = i2 = i3 = 0;
#pragma unroll
                for (int q = 0; q < 40; ++q) {
                    float v = ((used >> q) & 1ull) ? NEG7 : rv[q];
                    if (v > v3) {
                        if (v > v1) {
                            if (v > v0) { v3 = v2; i3 = i2; v2 = v1; i2 = i1; v1 = v0; i1 = i0; v0 = v; i0 = q; }
                            else        { v3 = v2; i3 = i2; v2 = v1; i2 = i1; v1 = v; i1 = q; }
                        } else {
                            if (v > v2) { v3 = v2; i3 = i2; v2 = v; i2 = q; }
                            else        { v3 = v; i3 = q; }
                        }
                    }
                }
            }
            myidx = wv * 2500 + (i0 >> 2) * 256 + lane * 4 + (i0 & 3);
        }
    }
    if (lane < 32) {
        size_t o = ((size_t)row * 8 + wv) * 32 + lane;
        candV[o] = keepv;
        candI[o] = keepi;
    }
}

// ---------------------------------------------------------------------------
// K7b (round-16 PROVEN): merge 256 candidates -> top-64 (stable); f64
//     rescore; final top-30 by (rescored desc, idx asc); m_output.
// ---------------------------------------------------------------------------
__global__ __launch_bounds__(256) void k7b_final(const float* __restrict__ candV,
                                                 const int* __restrict__ candI,
                                                 const float* __restrict__ outs,
                                                 const float* __restrict__ W,
                                                 const float* __restrict__ bo,
                                                 float* __restrict__ mOut,
                                                 float* __restrict__ sOut) {
    __shared__ float selv[64];
    __shared__ int   seli[64];
    __shared__ float resv[64];
    __shared__ float redm[4];
    __shared__ __align__(16) float orow[H_];

    int row = blockIdx.x;
    int t = threadIdx.x;
    int lane = t & 63, wid = t >> 6;

    if (wid != 0) {
        for (int i = t - 64; i < H_; i += 192)
            orow[i] = outs[(size_t)row * H_ + i];
    } else {
        float cv[4]; int ci[4];
#pragma unroll
        for (int q = 0; q < 4; ++q) {
            size_t o = (size_t)row * 256 + q * 64 + lane;
            cv[q] = candV[o];
            ci[q] = candI[o];
        }
        float lv = cv[0]; int lix = ci[0]; int ls = 0;
#pragma unroll
        for (int q = 1; q < 4; ++q)
            if (cv[q] > lv || (cv[q] == lv && ci[q] < lix)) { lv = cv[q]; lix = ci[q]; ls = q; }

#pragma unroll 1
        for (int r = 0; r < 64; ++r) {
            float bv = lv; int bi = lix;
#pragma unroll
            for (int m = 1; m < 64; m <<= 1) {
                float ov = __shfl_xor(bv, m);
                int   oi = __shfl_xor(bi, m);
                if (ov > bv || (ov == bv && oi < bi)) { bv = ov; bi = oi; }
            }
            if (lane == r) { selv[r] = bv; seli[r] = bi; }
            if (lix == bi) {
#pragma unroll
                for (int q = 0; q < 4; ++q) cv[q] = (ls == q) ? NEG7 : cv[q];
                lv = cv[0]; lix = ci[0]; ls = 0;
#pragma unroll
                for (int q = 1; q < 4; ++q)
                    if (cv[q] > lv || (cv[q] == lv && ci[q] < lix)) { lv = cv[q]; lix = ci[q]; ls = q; }
            }
        }
    }
    __syncthreads();

    {
        float ms = fabsf(orow[t]) + fabsf(orow[t + 256]);
#pragma unroll
        for (int m = 1; m < 64; m <<= 1) ms += __shfl_xor(ms, m);
        if (lane == 0) redm[wid] = ms;
    }

    {
        int c = t >> 2, q = t & 3;
        int gidx = seli[c];
        const float4* w4 = (const float4*)(W + (size_t)gidx * H_);
        const float4* o4 = (const float4*)orow;
        double acc = 0.0;
#pragma unroll 8
        for (int i2 = 0; i2 < 32; ++i2) {
            float4 wv4 = w4[i2 * 4 + q];
            float4 ov4 = o4[i2 * 4 + q];
            acc += (double)wv4.x * (double)ov4.x + (double)wv4.y * (double)ov4.y
                 + (double)wv4.z * (double)ov4.z + (double)wv4.w * (double)ov4.w;
        }
        acc += __shfl_xor(acc, 1);
        acc += __shfl_xor(acc, 2);
        if (q == 0) resv[c] = (float)(acc + (double)bo[gidx]);
    }
    __syncthreads();

    if (t == 0)
        mOut[row] = (redm[0] + redm[1] + redm[2] + redm[3] > 0.f) ? 1.f : 0.f;

    if (t < 64) {
        float v = resv[t];
        int idx = seli[t];
#pragma unroll 1
        for (int r = 0; r < MV_; ++r) {
            float bv = v; int bi = idx;
#pragma unroll
            for (int m = 1; m < 64; m <<= 1) {
                float ov = __shfl_xor(bv, m);
                int   oi = __shfl_xor(bi, m);
                if (ov > bv || (ov == bv && oi < bi)) { bv = ov; bi = oi; }
            }
            if (t == 0)
                sOut[(size_t)row * MV_ + r] = (bv <= 0.0f) ? 0.0f : (float)bi;
            if (idx == bi) v = NEG7;
        }
    }
}

// ---------------------------------------------------------------------------
extern "C" void kernel_launch(void* const* d_in, const int* in_sizes, int n_in,
                              void* d_out, int out_size, void* d_ws, size_t ws_size,
                              hipStream_t stream) {
    const float* z      = (const float*)d_in[0];
    const int*   seq    = (const int*)d_in[1];
    const int*   length = (const int*)d_in[2];
    const float* Ew     = (const float*)d_in[3];
    const float* W_l2h  = (const float*)d_in[4];
    const float* b_l2h  = (const float*)d_in[5];
    const float* W_ih   = (const float*)d_in[6];
    const float* W_hh   = (const float*)d_in[7];
    const float* b_ih   = (const float*)d_in[8];
    const float* b_hh   = (const float*)d_in[9];
    const float* W_out  = (const float*)d_in[10];
    const float* b_out  = (const float*)d_in[11];

    float* out = (float*)d_out;

    double* emb_d = (double*)d_ws;               // 2048*256 f64 (A16 overlay after k3)
    double* gi_d  = emb_d + 524288;              // 2048*1536 f64 (W16 overlay after k4)
    double* hstep = gi_d + 3145728;              // 64 x 16384 f64 per-step h buffers (8MB)
    float*  outs  = (float*)(hstep + 1048576);   // 2048*512 f32
    float*  candV = outs + 1048576;              // 2048*256 f32
    int*    candI = (int*)(candV + (size_t)BS_ * 256);   // 2048*256 i32
    short*  A16   = (short*)emb_d;               // 2048*512 bf16 (emb dead after k3)
    short*  W16   = (short*)gi_d;                // 20000*512 bf16 (gi dead after k4)

    float* pOut = out;                           // 2048*20000
    float* sOut = out + (size_t)BS_ * V_;        // 2048*30
    float* mOut = sOut + (size_t)BS_ * MV_;      // 2048

    k12<<<BS_ + 64 + 1008, 256, 0, stream>>>(seq, Ew, z, W_l2h, b_l2h, emb_d, hstep);
    k3_gi<<<dim3(24, 32), 256, 0, stream>>>(emb_d, W_ih, b_ih, gi_d);
    k4_gru<<<NB4, 256, 0, stream>>>(gi_d, W_hh, b_hh, length, hstep, outs, A16);
    k_prep2<<<5000, 256, 0, stream>>>(W_out, W16);
    k5_mfma<<<1264, 256, 0, stream>>>(A16, W16, b_out, pOut);
    k7a_cand<<<BS_, 512, 0, stream>>>(pOut, candV, candI);
    k7b_final<<<BS_, 256, 0, stream>>>(candV, candI, outs, W_out, b_out, mOut, sOut);
}

// Round 13
// 604.327 us; speedup vs baseline: 1.0669x; 1.0669x over previous
//
#include <hip/hip_runtime.h>
#include <hip/hip_bf16.h>
#include <math.h>

// Problem constants
#define B_ 32
#define S_ 64
#define MV_ 30
#define V_ 20000
#define E_ 256
#define H_ 512
#define L_ 128
#define H3_ 1536
#define BS_ 2048   // B*S
#define NB4 256    // k4 grid blocks (persistent, co-resident; 8 groups x 32)
#define NEG7 -3.0e38f
#define SENT 0xFFF8000000000000ULL   // quiet NaN; h is always finite -> unreachable

typedef __attribute__((ext_vector_type(8))) short short8v;  // 8 bf16 (4 VGPRs)
typedef __attribute__((ext_vector_type(4))) float f32x4;
typedef unsigned long long ull_;

// ---------------------------------------------------------------------------
// K12: blocks [0,2048): k1 multi-hot embed body (verbatim);
//      blocks [2048,2112): k2 h0 body (grouped packing, step-0 buffer);
//      blocks [2112,3120): NaN-sentinel init of step buffers 1..63 (8.25MB).
// hstep layout: hstep[s*16384 + g*2048 + u*4 + b_in_group], s = 0..63
// ---------------------------------------------------------------------------
__global__ __launch_bounds__(256) void k12(const int* __restrict__ seq,
                                           const float* __restrict__ Ew,
                                           const float* __restrict__ z,
                                           const float* __restrict__ Wl,
                                           const float* __restrict__ bl,
                                           double* __restrict__ emb,
                                           double* __restrict__ hstep) {
    __shared__ int sidx[MV_];
    int bid = blockIdx.x;
    int t = threadIdx.x;
    if (bid < BS_) {
        int row = bid;
        if (t < MV_) sidx[t] = seq[row * MV_ + t];
        __syncthreads();
        double acc = 0.0;
        for (int i = 0; i < MV_; ++i) {
            int id = sidx[i];
            if (id == 0) continue;
            bool dup = false;
            for (int q = 0; q < i; ++q) dup = dup || (sidx[q] == id);
            if (!dup) acc += (double)Ew[(size_t)id * E_ + t];
        }
        emb[(size_t)row * E_ + t] = tanh(acc);
    } else if (bid < BS_ + 64) {
        int o = (bid - BS_) * 256 + t;   // < 16384
        int b = o >> 9;
        int j = o & 511;
        const float4* zr = (const float4*)(z + (size_t)b * L_);
        const float4* wr = (const float4*)(Wl + (size_t)j * L_);
        double acc = (double)bl[j];
#pragma unroll
        for (int k = 0; k < L_ / 4; ++k) {
            float4 a = zr[k];
            float4 w = wr[k];
            acc += (double)a.x * (double)w.x + (double)a.y * (double)w.y
                 + (double)a.z * (double)w.z + (double)a.w * (double)w.w;
        }
        hstep[(size_t)(b >> 2) * 2048 + j * 4 + (b & 3)] = acc;
    } else {
        // sentinel fill for steps 1..63: 63*16384 = 1,032,192 ulls
        ull_* hs = (ull_*)hstep;
        size_t i = (size_t)(bid - (BS_ + 64)) * 1024 + (size_t)t * 4;
        hs[16384 + i + 0] = SENT;
        hs[16384 + i + 1] = SENT;
        hs[16384 + i + 2] = SENT;
        hs[16384 + i + 3] = SENT;
    }
}

// ---------------------------------------------------------------------------
// K3: Gi = emb @ W_ih^T + b_ih  (2048x1536, K=256), f64. 64x64 tile, 4x4/thread.
//     Output PACKED for k4: gi_p[(((s*512 + unit)*3 + gate)*32 + b)]
// ---------------------------------------------------------------------------
__global__ __launch_bounds__(256) void k3_gi(const double* __restrict__ A,
                                             const float* __restrict__ Bm,
                                             const float* __restrict__ bih,
                                             double* __restrict__ gi) {
    __shared__ double As[16][66];
    __shared__ double Bs[16][66];
    int t = threadIdx.x;
    int n0 = blockIdx.x * 64;   // 24
    int m0 = blockIdx.y * 64;   // 32
    int tx = t & 15, ty = t >> 4;
    int ml = t >> 2;
    int kl = (t & 3) * 4;
    double acc[4][4];
#pragma unroll
    for (int i = 0; i < 4; ++i)
#pragma unroll
        for (int j = 0; j < 4; ++j) acc[i][j] = 0.0;

    for (int kt = 0; kt < 256; kt += 16) {
        double4 av = *(const double4*)(A + (size_t)(m0 + ml) * 256 + kt + kl);
        float4 bv = *(const float4*)(Bm + (size_t)(n0 + ml) * 256 + kt + kl);
        As[kl + 0][ml] = av.x; As[kl + 1][ml] = av.y; As[kl + 2][ml] = av.z; As[kl + 3][ml] = av.w;
        Bs[kl + 0][ml] = (double)bv.x; Bs[kl + 1][ml] = (double)bv.y;
        Bs[kl + 2][ml] = (double)bv.z; Bs[kl + 3][ml] = (double)bv.w;
        __syncthreads();
#pragma unroll
        for (int kk = 0; kk < 16; ++kk) {
            double2 a01 = *(const double2*)&As[kk][ty * 4];
            double2 a23 = *(const double2*)&As[kk][ty * 4 + 2];
            double2 b01 = *(const double2*)&Bs[kk][tx * 4];
            double2 b23 = *(const double2*)&Bs[kk][tx * 4 + 2];
            double am[4] = {a01.x, a01.y, a23.x, a23.y};
            double bn[4] = {b01.x, b01.y, b23.x, b23.y};
#pragma unroll
            for (int i = 0; i < 4; ++i)
#pragma unroll
                for (int j = 0; j < 4; ++j) acc[i][j] += am[i] * bn[j];
        }
        __syncthreads();
    }
#pragma unroll
    for (int i = 0; i < 4; ++i) {
        int m = m0 + ty * 4 + i;
        int bb = m >> 6, ss = m & 63;
#pragma unroll
        for (int j = 0; j < 4; ++j) {
            int n = n0 + tx * 4 + j;
            int g = n >> 9, u = n & 511;
            gi[(((size_t)(ss * 512 + u)) * 3 + g) * 32 + bb] = acc[i][j] + (double)bih[n];
        }
    }
}

// ---------------------------------------------------------------------------
// K4 (round-16, PROVEN 265us): sentinel data-poll + two-phase chunked overlap.
// ---------------------------------------------------------------------------
__global__ __launch_bounds__(256, 1) void k4_gru(const double* __restrict__ gi,
                                                 const float* __restrict__ whh,
                                                 const float* __restrict__ bhh,
                                                 const int* __restrict__ length,
                                                 double* __restrict__ hstep,
                                                 float* __restrict__ outs,
                                                 short* __restrict__ A16) {
    __shared__ double hl[2112];               // group h: idx = e + (e>>7)*4
    __shared__ double part[2][4][16][13];     // [parity][wave][ul][gate*4+b], pad 13

    int t = threadIdx.x;
    int wv = t >> 6;
    int lane = t & 63;
    int bid = blockIdx.x;
    int g = bid & 7;          // group
    int beta = bid >> 3;      // block-in-group 0..31

    // matvec lane mapping: (ul, ks); wave wv covers k in [wv*128, wv*128+128)
    int ul = lane >> 2, ks = lane & 3;

    // ---- W_hh slice into registers: rows (gate*512 + beta*16 + ul),
    //      cols [wv*128 + ks*32, +32) = 8 float4 per gate ----
    const float* wbase = whh + ((size_t)(beta * 16 + ul)) * 512 + wv * 128 + ks * 32;
    float4 w0r[8], w1r[8], w2r[8];
#pragma unroll
    for (int c = 0; c < 8; ++c) {
        w0r[c] = *(const float4*)(wbase + c * 4);
        w1r[c] = *(const float4*)(wbase + 512 * 512 + c * 4);
        w2r[c] = *(const float4*)(wbase + 1024 * 512 + c * 4);
    }

    // ---- initial h (step 0), group-local 16KB (plain loads; pre-k4 data) ----
    const double* hg0 = hstep + (size_t)g * 2048;
    {
#pragma unroll
        for (int j = 0; j < 8; ++j) {
            int e = t + j * 256;
            hl[e + ((e >> 7) << 2)] = hg0[e];
        }
    }
    __syncthreads();

    // wave0 per-lane elementwise state: lane = (u2 0..15, b2 0..3)
    int u2 = lane >> 2, b2 = lane & 3;
    int u_g = beta * 16 + u2;      // global unit
    int b_g = g * 4 + b2;          // global batch
    double gr = 0.0, gz = 0.0, gn = 0.0, bhr_ = 0.0, bhz_ = 0.0, bhn_ = 0.0;
    double hv = 0.0;               // own h_prev in register
    int len = 0;
    if (wv == 0) {
        bhr_ = (double)bhh[u_g];
        bhz_ = (double)bhh[u_g + 512];
        bhn_ = (double)bhh[u_g + 1024];
        len = length[b_g];
        hv = hg0[u_g * 4 + b2];
        size_t gb = ((size_t)u_g * 3) * 32 + b_g;
        gr = gi[gb]; gz = gi[gb + 32]; gn = gi[gb + 64];
    }

    const double* hr = &hl[(wv * 128 + ks * 32) * 4 + ((wv * 4 + ks) << 2)];

    for (int s = 0; s < S_; ++s) {
        int par = s & 1;
        ull_ ta[4], tb[4];
        const ull_* src = (const ull_*)(hstep + (size_t)s * 16384 + (size_t)g * 2048)
                          + wv * 512;
        if (s > 0) {
            // ---- phase A: poll even-j chunks (coalesced lane-major) ----
            while (true) {
                bool ok = true;
#pragma unroll
                for (int j = 0; j < 4; ++j) {
                    ta[j] = __hip_atomic_load(&src[(2 * j) * 64 + lane],
                                              __ATOMIC_RELAXED, __HIP_MEMORY_SCOPE_AGENT);
                    ok = ok && (ta[j] != SENT);
                }
                if (__all(ok)) break;
                __builtin_amdgcn_s_sleep(1);
            }
            // first-try odd-j loads: in flight during stage + matvec A
#pragma unroll
            for (int j = 0; j < 4; ++j)
                tb[j] = __hip_atomic_load(&src[(2 * j + 1) * 64 + lane],
                                          __ATOMIC_RELAXED, __HIP_MEMORY_SCOPE_AGENT);
            asm volatile("" ::: "memory");
            {
                ull_* hlu = (ull_*)hl;
#pragma unroll
                for (int j = 0; j < 4; ++j) {
                    int e = wv * 512 + (2 * j) * 64 + lane;
                    hlu[e + ((e >> 7) << 2)] = ta[j];
                }
            }
        }

        double a0[4] = {0, 0, 0, 0}, a1[4] = {0, 0, 0, 0}, a2[4] = {0, 0, 0, 0};
        // ---- matvec phase A: c = 0..3 (k_local in even-j chunks) ----
#pragma unroll
        for (int c = 0; c < 4; ++c) {
            const double* hp = hr + c * 16;
            double2 hA0 = *(const double2*)(hp + 0),  hB0 = *(const double2*)(hp + 2);
            double2 hA1 = *(const double2*)(hp + 4),  hB1 = *(const double2*)(hp + 6);
            double2 hA2 = *(const double2*)(hp + 8),  hB2 = *(const double2*)(hp + 10);
            double2 hA3 = *(const double2*)(hp + 12), hB3 = *(const double2*)(hp + 14);
            float4 w0 = w0r[c], w1 = w1r[c], w2 = w2r[c];
            { double d0 = (double)w0.x, d1 = (double)w1.x, d2 = (double)w2.x;
              a0[0] += hA0.x * d0; a0[1] += hA0.y * d0; a0[2] += hB0.x * d0; a0[3] += hB0.y * d0;
              a1[0] += hA0.x * d1; a1[1] += hA0.y * d1; a1[2] += hB0.x * d1; a1[3] += hB0.y * d1;
              a2[0] += hA0.x * d2; a2[1] += hA0.y * d2; a2[2] += hB0.x * d2; a2[3] += hB0.y * d2; }
            { double d0 = (double)w0.y, d1 = (double)w1.y, d2 = (double)w2.y;
              a0[0] += hA1.x * d0; a0[1] += hA1.y * d0; a0[2] += hB1.x * d0; a0[3] += hB1.y * d0;
              a1[0] += hA1.x * d1; a1[1] += hA1.y * d1; a1[2] += hB1.x * d1; a1[3] += hB1.y * d1;
              a2[0] += hA1.x * d2; a2[1] += hA1.y * d2; a2[2] += hB1.x * d2; a2[3] += hB1.y * d2; }
            { double d0 = (double)w0.z, d1 = (double)w1.z, d2 = (double)w2.z;
              a0[0] += hA2.x * d0; a0[1] += hA2.y * d0; a0[2] += hB2.x * d0; a0[3] += hB2.y * d0;
              a1[0] += hA2.x * d1; a1[1] += hA2.y * d1; a1[2] += hB2.x * d1; a1[3] += hB2.y * d1;
              a2[0] += hA2.x * d2; a2[1] += hA2.y * d2; a2[2] += hB2.x * d2; a2[3] += hB2.y * d2; }
            { double d0 = (double)w0.w, d1 = (double)w1.w, d2 = (double)w2.w;
              a0[0] += hA3.x * d0; a0[1] += hA3.y * d0; a0[2] += hB3.x * d0; a0[3] += hB3.y * d0;
              a1[0] += hA3.x * d1; a1[1] += hA3.y * d1; a1[2] += hB3.x * d1; a1[3] += hB3.y * d1;
              a2[0] += hA3.x * d2; a2[1] += hA3.y * d2; a2[2] += hB3.x * d2; a2[3] += hB3.y * d2; }
        }

        if (s > 0) {
            // ---- phase B: verify/complete odd-j chunks, stage ----
            while (true) {
                bool ok = true;
#pragma unroll
                for (int j = 0; j < 4; ++j) ok = ok && (tb[j] != SENT);
                if (__all(ok)) break;
                __builtin_amdgcn_s_sleep(1);
#pragma unroll
                for (int j = 0; j < 4; ++j)
                    tb[j] = __hip_atomic_load(&src[(2 * j + 1) * 64 + lane],
                                              __ATOMIC_RELAXED, __HIP_MEMORY_SCOPE_AGENT);
            }
            asm volatile("" ::: "memory");
            {
                ull_* hlu = (ull_*)hl;
#pragma unroll
                for (int j = 0; j < 4; ++j) {
                    int e = wv * 512 + (2 * j + 1) * 64 + lane;
                    hlu[e + ((e >> 7) << 2)] = tb[j];
                }
            }
        }

        // ---- matvec phase B: c = 4..7 (k_local in odd-j chunks) ----
#pragma unroll
        for (int c = 4; c < 8; ++c) {
            const double* hp = hr + c * 16;
            double2 hA0 = *(const double2*)(hp + 0),  hB0 = *(const double2*)(hp + 2);
            double2 hA1 = *(const double2*)(hp + 4),  hB1 = *(const double2*)(hp + 6);
            double2 hA2 = *(const double2*)(hp + 8),  hB2 = *(const double2*)(hp + 10);
            double2 hA3 = *(const double2*)(hp + 12), hB3 = *(const double2*)(hp + 14);
            float4 w0 = w0r[c], w1 = w1r[c], w2 = w2r[c];
            { double d0 = (double)w0.x, d1 = (double)w1.x, d2 = (double)w2.x;
              a0[0] += hA0.x * d0; a0[1] += hA0.y * d0; a0[2] += hB0.x * d0; a0[3] += hB0.y * d0;
              a1[0] += hA0.x * d1; a1[1] += hA0.y * d1; a1[2] += hB0.x * d1; a1[3] += hB0.y * d1;
              a2[0] += hA0.x * d2; a2[1] += hA0.y * d2; a2[2] += hB0.x * d2; a2[3] += hB0.y * d2; }
            { double d0 = (double)w0.y, d1 = (double)w1.y, d2 = (double)w2.y;
              a0[0] += hA1.x * d0; a0[1] += hA1.y * d0; a0[2] += hB1.x * d0; a0[3] += hB1.y * d0;
              a1[0] += hA1.x * d1; a1[1] += hA1.y * d1; a1[2] += hB1.x * d1; a1[3] += hB1.y * d1;
              a2[0] += hA1.x * d2; a2[1] += hA1.y * d2; a2[2] += hB1.x * d2; a2[3] += hB1.y * d2; }
            { double d0 = (double)w0.z, d1 = (double)w1.z, d2 = (double)w2.z;
              a0[0] += hA2.x * d0; a0[1] += hA2.y * d0; a0[2] += hB2.x * d0; a0[3] += hB2.y * d0;
              a1[0] += hA2.x * d1; a1[1] += hA2.y * d1; a1[2] += hB2.x * d1; a1[3] += hB2.y * d1;
              a2[0] += hA2.x * d2; a2[1] += hA2.y * d2; a2[2] += hB2.x * d2; a2[3] += hB2.y * d2; }
            { double d0 = (double)w0.w, d1 = (double)w1.w, d2 = (double)w2.w;
              a0[0] += hA3.x * d0; a0[1] += hA3.y * d0; a0[2] += hB3.x * d0; a0[3] += hB3.y * d0;
              a1[0] += hA3.x * d1; a1[1] += hA3.y * d1; a1[2] += hB3.x * d1; a1[3] += hB3.y * d1;
              a2[0] += hA3.x * d2; a2[1] += hA3.y * d2; a2[2] += hB3.x * d2; a2[3] += hB3.y * d2; }
        }

        // reduce over ks (lanes xor 1, 2)
#pragma unroll
        for (int b = 0; b < 4; ++b) {
            a0[b] += __shfl_xor(a0[b], 1); a0[b] += __shfl_xor(a0[b], 2);
            a1[b] += __shfl_xor(a1[b], 1); a1[b] += __shfl_xor(a1[b], 2);
            a2[b] += __shfl_xor(a2[b], 1); a2[b] += __shfl_xor(a2[b], 2);
        }
        if (ks == 0) {
#pragma unroll
            for (int b = 0; b < 4; ++b) {
                part[par][wv][ul][0 * 4 + b] = a0[b];
                part[par][wv][ul][1 * 4 + b] = a1[b];
                part[par][wv][ul][2 * 4 + b] = a2[b];
            }
        }
        __syncthreads();   // S1 (only barrier per step): partials visible

        if (wv == 0) {
            double s0 = part[par][0][u2][0 * 4 + b2] + part[par][1][u2][0 * 4 + b2]
                      + part[par][2][u2][0 * 4 + b2] + part[par][3][u2][0 * 4 + b2];
            double s1 = part[par][0][u2][1 * 4 + b2] + part[par][1][u2][1 * 4 + b2]
                      + part[par][2][u2][1 * 4 + b2] + part[par][3][u2][1 * 4 + b2];
            double s2 = part[par][0][u2][2 * 4 + b2] + part[par][1][u2][2 * 4 + b2]
                      + part[par][2][u2][2 * 4 + b2] + part[par][3][u2][2 * 4 + b2];
            double r  = 1.0 / (1.0 + exp(-(gr + s0 + bhr_)));
            double zt = 1.0 / (1.0 + exp(-(gz + s1 + bhz_)));
            double n  = tanh(gn + r * (s2 + bhn_));
            double hn_ = (1.0 - zt) * n + zt * hv;
            hv = hn_;
            if (s < S_ - 1) {
                // publish to write-once step buffer; the data IS the flag
                ull_* hdst = (ull_*)(hstep + (size_t)(s + 1) * 16384 + (size_t)g * 2048);
                // (beta*16+u2)*4 + b2 == beta*64 + lane -> fully coalesced 512B store
                __hip_atomic_store(&hdst[beta * 64 + lane],
                                   __builtin_bit_cast(ull_, hn_),
                                   __ATOMIC_RELAXED, __HIP_MEMORY_SCOPE_AGENT);
                // gi prefetch for s+1 (overlaps consumers' polls)
                size_t gb = ((size_t)((s + 1) * 512 + u_g) * 3) * 32 + b_g;
                gr = gi[gb]; gz = gi[gb + 32]; gn = gi[gb + 64];
            }
            float ov = (s < len) ? (float)hn_ : 0.0f;
            size_t oidx = (size_t)(b_g * 64 + s) * H_ + u_g;
            outs[oidx] = ov;
            {   // fused bf16 conversion (was k_prep2's A-half)
                unsigned u = __builtin_bit_cast(unsigned, ov);
                A16[oidx] = (short)((u + 0x7FFFu + ((u >> 16) & 1u)) >> 16);
            }
        }
    }
}

// ---------------------------------------------------------------------------
// bf16 helpers + prep kernel (W16 only): blocks [0,5000) convert W_out.
// ---------------------------------------------------------------------------
__device__ __forceinline__ unsigned short f2b_(float x) {
    unsigned u = __builtin_bit_cast(unsigned, x);
    return (unsigned short)((u + 0x7FFFu + ((u >> 16) & 1u)) >> 16);   // RNE
}
__device__ __forceinline__ short8v pack8_(float4 a, float4 b) {
    short8v r;
    r[0] = (short)f2b_(a.x); r[1] = (short)f2b_(a.y);
    r[2] = (short)f2b_(a.z); r[3] = (short)f2b_(a.w);
    r[4] = (short)f2b_(b.x); r[5] = (short)f2b_(b.y);
    r[6] = (short)f2b_(b.z); r[7] = (short)f2b_(b.w);
    return r;
}
__global__ __launch_bounds__(256) void k_prep2(const float* __restrict__ Wsrc,
                                               short* __restrict__ W16) {
    int i = blockIdx.x * 256 + threadIdx.x;  // < 1,280,000
    float4 a = *(const float4*)&Wsrc[(size_t)i * 8];
    float4 b = *(const float4*)&Wsrc[(size_t)i * 8 + 4];
    *(short8v*)&W16[(size_t)i * 8] = pack8_(a, b);
}

// ---------------------------------------------------------------------------
// K5 (round-16 PROVEN): p = sigmoid(A16 @ W16^T + b_out), bf16 MFMA. BK=64.
//     128x128 tile, 4 waves (2x2 of 64x64), LDS stride 72. Grid 2512.
//     [R21 note: 128x256 retile measured +38us WORSE — de-coalesced 1-thread-
//      per-row B staging. Do not retry without per-kernel timing.]
// ---------------------------------------------------------------------------
#define LDK5 72
__global__ __launch_bounds__(256, 2) void k5_mfma(const short* __restrict__ A16,  // 2048x512 bf16
                                                  const short* __restrict__ W16,  // 20000x512 bf16
                                                  const float* __restrict__ bo,
                                                  float* __restrict__ pOut) {
    __shared__ short As[128 * LDK5];   // 18.4KB
    __shared__ short Bs[128 * LDK5];
    int t = threadIdx.x;
    int bid = blockIdx.x;                       // 0..2511
    int swz = (bid & 7) * 314 + (bid >> 3);     // XCD swizzle (bijective, 2512=8*314)
    int m0 = (swz & 15) * 128;
    int n0 = (swz >> 4) * 128;
    int lane = t & 63, wv = t >> 6;
    int wr = wv >> 1, wc = wv & 1;              // wave -> 64x64 quadrant
    int ml = t >> 1;                            // 0..127 (staging row)
    int kl = (t & 1) * 32;                      // 0 or 32 (staging k-offset)

    const short* Arow = A16 + (size_t)(m0 + ml) * H_ + kl;
    int vrow = n0 + ml;
    bool vok = vrow < V_;
    const short* Wrow = W16 + (size_t)(vok ? vrow : 0) * H_ + kl;
    short8v zz = (short8v){0, 0, 0, 0, 0, 0, 0, 0};

    f32x4 acc[4][4];
#pragma unroll
    for (int i = 0; i < 4; ++i)
#pragma unroll
        for (int j = 0; j < 4; ++j) acc[i][j] = (f32x4){0.f, 0.f, 0.f, 0.f};

    int ko = lane >> 4;       // 0..3 (k-group of 8)
    int rr = lane & 15;       // fragment row/col

    for (int kt = 0; kt < H_; kt += 64) {
        short8v a0 = *(const short8v*)(Arow + kt);
        short8v a1 = *(const short8v*)(Arow + kt + 8);
        short8v a2 = *(const short8v*)(Arow + kt + 16);
        short8v a3 = *(const short8v*)(Arow + kt + 24);
        short8v b0 = vok ? *(const short8v*)(Wrow + kt) : zz;
        short8v b1 = vok ? *(const short8v*)(Wrow + kt + 8) : zz;
        short8v b2 = vok ? *(const short8v*)(Wrow + kt + 16) : zz;
        short8v b3 = vok ? *(const short8v*)(Wrow + kt + 24) : zz;
        *(short8v*)&As[ml * LDK5 + kl]      = a0;
        *(short8v*)&As[ml * LDK5 + kl + 8]  = a1;
        *(short8v*)&As[ml * LDK5 + kl + 16] = a2;
        *(short8v*)&As[ml * LDK5 + kl + 24] = a3;
        *(short8v*)&Bs[ml * LDK5 + kl]      = b0;
        *(short8v*)&Bs[ml * LDK5 + kl + 8]  = b1;
        *(short8v*)&Bs[ml * LDK5 + kl + 16] = b2;
        *(short8v*)&Bs[ml * LDK5 + kl + 24] = b3;
        __syncthreads();

#pragma unroll
        for (int kh = 0; kh < 2; ++kh) {
            short8v af[4], bf[4];
#pragma unroll
            for (int i = 0; i < 4; ++i)
                af[i] = *(const short8v*)&As[(wr * 64 + i * 16 + rr) * LDK5 + kh * 32 + ko * 8];
#pragma unroll
            for (int j = 0; j < 4; ++j)
                bf[j] = *(const short8v*)&Bs[(wc * 64 + j * 16 + rr) * LDK5 + kh * 32 + ko * 8];
#pragma unroll
            for (int i = 0; i < 4; ++i)
#pragma unroll
                for (int j = 0; j < 4; ++j)
                    acc[i][j] = __builtin_amdgcn_mfma_f32_16x16x32_bf16(af[i], bf[j], acc[i][j], 0, 0, 0);
        }
        __syncthreads();
    }

    int cr4 = (lane >> 4) * 4;
    float bov[4];
#pragma unroll
    for (int j = 0; j < 4; ++j) {
        int v = n0 + wc * 64 + j * 16 + rr;
        bov[j] = (v < V_) ? bo[v] : 0.f;
    }
#pragma unroll
    for (int i = 0; i < 4; ++i) {
#pragma unroll
        for (int j = 0; j < 4; ++j) {
            int v = n0 + wc * 64 + j * 16 + rr;
            if (v < V_) {
#pragma unroll
                for (int r = 0; r < 4; ++r) {
                    int m = m0 + wr * 64 + i * 16 + cr4 + r;
                    float x = acc[i][j][r] + bov[j];
                    pOut[(size_t)m * V_ + v] = 1.0f / (1.0f + expf(-x));
                }
            }
        }
    }
}

// ---------------------------------------------------------------------------
// K7a (round-20 PROVEN): per-wave top-32, sorted-top-4 maintenance.
// ---------------------------------------------------------------------------
__global__ __launch_bounds__(512) void k7a_cand(const float* __restrict__ pOut,
                                                float* __restrict__ candV,
                                                int* __restrict__ candI) {
    int row = blockIdx.x;
    int t = threadIdx.x;
    int wv = t >> 6;          // chunk 0..7 (2500 cols each)
    int lane = t & 63;
    const float* rowp = pOut + (size_t)row * V_ + wv * 2500;

    float rv[40];
#pragma unroll
    for (int q4 = 0; q4 < 10; ++q4) {
        int base = q4 * 256 + lane * 4;
        float4 v4 = *(const float4*)(rowp + base);   // tails stay inside d_out; masked below
        float vv[4] = {v4.x, v4.y, v4.z, v4.w};
#pragma unroll
        for (int c = 0; c < 4; ++c) {
            int li = base + c;
            int col = wv * 2500 + li;
            bool ok = (li < 2500) && (col >= 3);
            rv[q4 * 4 + c] = ok ? vv[c] : NEG7;
        }
    }

    // sorted top-4 (v desc, q asc): stable strict-> insertion in q order
    float v0 = NEG7, v1 = NEG7, v2 = NEG7, v3 = NEG7;
    int   i0 = 0,    i1 = 0,    i2 = 0,    i3 = 0;
#pragma unroll
    for (int q = 0; q < 40; ++q) {
        float v = rv[q];
        if (v > v3) {
            if (v > v1) {
                if (v > v0) { v3 = v2; i3 = i2; v2 = v1; i2 = i1; v1 = v0; i1 = i0; v0 = v; i0 = q; }
                else        { v3 = v2; i3 = i2; v2 = v1; i2 = i1; v1 = v; i1 = q; }
            } else {
                if (v > v2) { v3 = v2; i3 = i2; v2 = v; i2 = q; }
                else        { v3 = v; i3 = q; }
            }
        }
    }

    ull_ used = 0;
    int pops = 0;
    int myidx = wv * 2500 + (i0 >> 2) * 256 + lane * 4 + (i0 & 3);

    float keepv = NEG7; int keepi = 0;
#pragma unroll 1
    for (int r = 0; r < 32; ++r) {
        float bv = v0; int bi = myidx;
#pragma unroll
        for (int m = 1; m < 64; m <<= 1) {
            float ov = __shfl_xor(bv, m);
            int   oi = __shfl_xor(bi, m);
            if (ov > bv || (ov == bv && oi < bi)) { bv = ov; bi = oi; }
        }
        if (lane == r) { keepv = bv; keepi = bi; }
        if (myidx == bi) {           // this lane won (idx unique -> exactly one)
            used |= (1ull << i0);
            v0 = v1; i0 = i1; v1 = v2; i1 = i2; v2 = v3; i2 = i3; v3 = NEG7; i3 = 0;
            if (++pops == 4) {       // list exhausted: rare rebuild (excl. used)
                pops = 0;
                v0 = v1 = v2 = v3 = NEG7; i0 = i1 = i2 = i3 = 0;
#pragma unroll
                for (int q = 0; q < 40; ++q) {
                    float v = ((used >> q) & 1ull) ? NEG7 : rv[q];
                    if (v > v3) {
                        if (v > v1) {
                            if (v > v0) { v3 = v2; i3 = i2; v2 = v1; i2 = i1; v1 = v0; i1 = i0; v0 = v; i0 = q; }
                            else        { v3 = v2; i3 = i2; v2 = v1; i2 = i1; v1 = v; i1 = q; }
                        } else {
                            if (v > v2) { v3 = v2; i3 = i2; v2 = v; i2 = q; }
                            else        { v3 = v; i3 = q; }
                        }
                    }
                }
            }
            myidx = wv * 2500 + (i0 >> 2) * 256 + lane * 4 + (i0 & 3);
        }
    }
    if (lane < 32) {
        size_t o = ((size_t)row * 8 + wv) * 32 + lane;
        candV[o] = keepv;
        candI[o] = keepi;
    }
}

// ---------------------------------------------------------------------------
// K7b (round-16 PROVEN): merge 256 candidates -> top-64 (stable); f64
//     rescore; final top-30 by (rescored desc, idx asc); m_output.
// ---------------------------------------------------------------------------
__global__ __launch_bounds__(256) void k7b_final(const float* __restrict__ candV,
                                                 const int* __restrict__ candI,
                                                 const float* __restrict__ outs,
                                                 const float* __restrict__ W,
                                                 const float* __restrict__ bo,
                                                 float* __restrict__ mOut,
                                                 float* __restrict__ sOut) {
    __shared__ float selv[64];
    __shared__ int   seli[64];
    __shared__ float resv[64];
    __shared__ float redm[4];
    __shared__ __align__(16) float orow[H_];

    int row = blockIdx.x;
    int t = threadIdx.x;
    int lane = t & 63, wid = t >> 6;

    if (wid != 0) {
        for (int i = t - 64; i < H_; i += 192)
            orow[i] = outs[(size_t)row * H_ + i];
    } else {
        float cv[4]; int ci[4];
#pragma unroll
        for (int q = 0; q < 4; ++q) {
            size_t o = (size_t)row * 256 + q * 64 + lane;
            cv[q] = candV[o];
            ci[q] = candI[o];
        }
        float lv = cv[0]; int lix = ci[0]; int ls = 0;
#pragma unroll
        for (int q = 1; q < 4; ++q)
            if (cv[q] > lv || (cv[q] == lv && ci[q] < lix)) { lv = cv[q]; lix = ci[q]; ls = q; }

#pragma unroll 1
        for (int r = 0; r < 64; ++r) {
            float bv = lv; int bi = lix;
#pragma unroll
            for (int m = 1; m < 64; m <<= 1) {
                float ov = __shfl_xor(bv, m);
                int   oi = __shfl_xor(bi, m);
                if (ov > bv || (ov == bv && oi < bi)) { bv = ov; bi = oi; }
            }
            if (lane == r) { selv[r] = bv; seli[r] = bi; }
            if (lix == bi) {
#pragma unroll
                for (int q = 0; q < 4; ++q) cv[q] = (ls == q) ? NEG7 : cv[q];
                lv = cv[0]; lix = ci[0]; ls = 0;
#pragma unroll
                for (int q = 1; q < 4; ++q)
                    if (cv[q] > lv || (cv[q] == lv && ci[q] < lix)) { lv = cv[q]; lix = ci[q]; ls = q; }
            }
        }
    }
    __syncthreads();

    {
        float ms = fabsf(orow[t]) + fabsf(orow[t + 256]);
#pragma unroll
        for (int m = 1; m < 64; m <<= 1) ms += __shfl_xor(ms, m);
        if (lane == 0) redm[wid] = ms;
    }

    {
        int c = t >> 2, q = t & 3;
        int gidx = seli[c];
        const float4* w4 = (const float4*)(W + (size_t)gidx * H_);
        const float4* o4 = (const float4*)orow;
        double acc = 0.0;
#pragma unroll 8
        for (int i2 = 0; i2 < 32; ++i2) {
            float4 wv4 = w4[i2 * 4 + q];
            float4 ov4 = o4[i2 * 4 + q];
            acc += (double)wv4.x * (double)ov4.x + (double)wv4.y * (double)ov4.y
                 + (double)wv4.z * (double)ov4.z + (double)wv4.w * (double)ov4.w;
        }
        acc += __shfl_xor(acc, 1);
        acc += __shfl_xor(acc, 2);
        if (q == 0) resv[c] = (float)(acc + (double)bo[gidx]);
    }
    __syncthreads();

    if (t == 0)
        mOut[row] = (redm[0] + redm[1] + redm[2] + redm[3] > 0.f) ? 1.f : 0.f;

    if (t < 64) {
        float v = resv[t];
        int idx = seli[t];
#pragma unroll 1
        for (int r = 0; r < MV_; ++r) {
            float bv = v; int bi = idx;
#pragma unroll
            for (int m = 1; m < 64; m <<= 1) {
                float ov = __shfl_xor(bv, m);
                int   oi = __shfl_xor(bi, m);
                if (ov > bv || (ov == bv && oi < bi)) { bv = ov; bi = oi; }
            }
            if (t == 0)
                sOut[(size_t)row * MV_ + r] = (bv <= 0.0f) ? 0.0f : (float)bi;
            if (idx == bi) v = NEG7;
        }
    }
}

// ---------------------------------------------------------------------------
extern "C" void kernel_launch(void* const* d_in, const int* in_sizes, int n_in,
                              void* d_out, int out_size, void* d_ws, size_t ws_size,
                              hipStream_t stream) {
    const float* z      = (const float*)d_in[0];
    const int*   seq    = (const int*)d_in[1];
    const int*   length = (const int*)d_in[2];
    const float* Ew     = (const float*)d_in[3];
    const float* W_l2h  = (const float*)d_in[4];
    const float* b_l2h  = (const float*)d_in[5];
    const float* W_ih   = (const float*)d_in[6];
    const float* W_hh   = (const float*)d_in[7];
    const float* b_ih   = (const float*)d_in[8];
    const float* b_hh   = (const float*)d_in[9];
    const float* W_out  = (const float*)d_in[10];
    const float* b_out  = (const float*)d_in[11];

    float* out = (float*)d_out;

    double* emb_d = (double*)d_ws;               // 2048*256 f64 (A16 overlay after k3)
    double* gi_d  = emb_d + 524288;              // 2048*1536 f64 (W16 overlay after k4)
    double* hstep = gi_d + 3145728;              // 64 x 16384 f64 per-step h buffers (8MB)
    float*  outs  = (float*)(hstep + 1048576);   // 2048*512 f32
    float*  candV = outs + 1048576;              // 2048*256 f32
    int*    candI = (int*)(candV + (size_t)BS_ * 256);   // 2048*256 i32
    short*  A16   = (short*)emb_d;               // 2048*512 bf16 (emb dead after k3)
    short*  W16   = (short*)gi_d;                // 20000*512 bf16 (gi dead after k4)

    float* pOut = out;                           // 2048*20000
    float* sOut = out + (size_t)BS_ * V_;        // 2048*30
    float* mOut = sOut + (size_t)BS_ * MV_;      // 2048

    k12<<<BS_ + 64 + 1008, 256, 0, stream>>>(seq, Ew, z, W_l2h, b_l2h, emb_d, hstep);
    k3_gi<<<dim3(24, 32), 256, 0, stream>>>(emb_d, W_ih, b_ih, gi_d);
    k4_gru<<<NB4, 256, 0, stream>>>(gi_d, W_hh, b_hh, length, hstep, outs, A16);
    k_prep2<<<5000, 256, 0, stream>>>(W_out, W16);
    k5_mfma<<<2512, 256, 0, stream>>>(A16, W16, b_out, pOut);
    k7a_cand<<<BS_, 512, 0, stream>>>(pOut, candV, candI);
    k7b_final<<<BS_, 256, 0, stream>>>(candV, candI, outs, W_out, b_out, mOut, sOut);
}

// Round 14
// 597.075 us; speedup vs baseline: 1.0799x; 1.0121x over previous
//
#include <hip/hip_runtime.h>
#include <hip/hip_bf16.h>
#include <math.h>

// Problem constants
#define B_ 32
#define S_ 64
#define MV_ 30
#define V_ 20000
#define E_ 256
#define H_ 512
#define L_ 128
#define H3_ 1536
#define BS_ 2048   // B*S
#define NB4 256    // k4 grid blocks (persistent, co-resident; 8 groups x 32)
#define NEG7 -3.0e38f
#define SENT 0xFFF8000000000000ULL   // quiet NaN; h is always finite -> unreachable

typedef __attribute__((ext_vector_type(8))) short short8v;  // 8 bf16 (4 VGPRs)
typedef __attribute__((ext_vector_type(4))) float f32x4;
typedef unsigned long long ull_;

// ---------------------------------------------------------------------------
// K12: blocks [0,2048): k1 multi-hot embed body (verbatim);
//      blocks [2048,2112): k2 h0 body (grouped packing, step-0 buffer);
//      blocks [2112,3120): NaN-sentinel init of step buffers 1..63 (8.25MB).
// hstep layout: hstep[s*16384 + g*2048 + u*4 + b_in_group], s = 0..63
// ---------------------------------------------------------------------------
__global__ __launch_bounds__(256) void k12(const int* __restrict__ seq,
                                           const float* __restrict__ Ew,
                                           const float* __restrict__ z,
                                           const float* __restrict__ Wl,
                                           const float* __restrict__ bl,
                                           double* __restrict__ emb,
                                           double* __restrict__ hstep) {
    __shared__ int sidx[MV_];
    int bid = blockIdx.x;
    int t = threadIdx.x;
    if (bid < BS_) {
        int row = bid;
        if (t < MV_) sidx[t] = seq[row * MV_ + t];
        __syncthreads();
        double acc = 0.0;
        for (int i = 0; i < MV_; ++i) {
            int id = sidx[i];
            if (id == 0) continue;
            bool dup = false;
            for (int q = 0; q < i; ++q) dup = dup || (sidx[q] == id);
            if (!dup) acc += (double)Ew[(size_t)id * E_ + t];
        }
        emb[(size_t)row * E_ + t] = tanh(acc);
    } else if (bid < BS_ + 64) {
        int o = (bid - BS_) * 256 + t;   // < 16384
        int b = o >> 9;
        int j = o & 511;
        const float4* zr = (const float4*)(z + (size_t)b * L_);
        const float4* wr = (const float4*)(Wl + (size_t)j * L_);
        double acc = (double)bl[j];
#pragma unroll
        for (int k = 0; k < L_ / 4; ++k) {
            float4 a = zr[k];
            float4 w = wr[k];
            acc += (double)a.x * (double)w.x + (double)a.y * (double)w.y
                 + (double)a.z * (double)w.z + (double)a.w * (double)w.w;
        }
        hstep[(size_t)(b >> 2) * 2048 + j * 4 + (b & 3)] = acc;
    } else {
        // sentinel fill for steps 1..63: 63*16384 = 1,032,192 ulls
        ull_* hs = (ull_*)hstep;
        size_t i = (size_t)(bid - (BS_ + 64)) * 1024 + (size_t)t * 4;
        hs[16384 + i + 0] = SENT;
        hs[16384 + i + 1] = SENT;
        hs[16384 + i + 2] = SENT;
        hs[16384 + i + 3] = SENT;
    }
}

// ---------------------------------------------------------------------------
// K3: Gi = emb @ W_ih^T + b_ih  (2048x1536, K=256), f64. 64x64 tile, 4x4/thread.
//     Output PACKED for k4: gi_p[(((s*512 + unit)*3 + gate)*32 + b)]
// ---------------------------------------------------------------------------
__global__ __launch_bounds__(256) void k3_gi(const double* __restrict__ A,
                                             const float* __restrict__ Bm,
                                             const float* __restrict__ bih,
                                             double* __restrict__ gi) {
    __shared__ double As[16][66];
    __shared__ double Bs[16][66];
    int t = threadIdx.x;
    int n0 = blockIdx.x * 64;   // 24
    int m0 = blockIdx.y * 64;   // 32
    int tx = t & 15, ty = t >> 4;
    int ml = t >> 2;
    int kl = (t & 3) * 4;
    double acc[4][4];
#pragma unroll
    for (int i = 0; i < 4; ++i)
#pragma unroll
        for (int j = 0; j < 4; ++j) acc[i][j] = 0.0;

    for (int kt = 0; kt < 256; kt += 16) {
        double4 av = *(const double4*)(A + (size_t)(m0 + ml) * 256 + kt + kl);
        float4 bv = *(const float4*)(Bm + (size_t)(n0 + ml) * 256 + kt + kl);
        As[kl + 0][ml] = av.x; As[kl + 1][ml] = av.y; As[kl + 2][ml] = av.z; As[kl + 3][ml] = av.w;
        Bs[kl + 0][ml] = (double)bv.x; Bs[kl + 1][ml] = (double)bv.y;
        Bs[kl + 2][ml] = (double)bv.z; Bs[kl + 3][ml] = (double)bv.w;
        __syncthreads();
#pragma unroll
        for (int kk = 0; kk < 16; ++kk) {
            double2 a01 = *(const double2*)&As[kk][ty * 4];
            double2 a23 = *(const double2*)&As[kk][ty * 4 + 2];
            double2 b01 = *(const double2*)&Bs[kk][tx * 4];
            double2 b23 = *(const double2*)&Bs[kk][tx * 4 + 2];
            double am[4] = {a01.x, a01.y, a23.x, a23.y};
            double bn[4] = {b01.x, b01.y, b23.x, b23.y};
#pragma unroll
            for (int i = 0; i < 4; ++i)
#pragma unroll
                for (int j = 0; j < 4; ++j) acc[i][j] += am[i] * bn[j];
        }
        __syncthreads();
    }
#pragma unroll
    for (int i = 0; i < 4; ++i) {
        int m = m0 + ty * 4 + i;
        int bb = m >> 6, ss = m & 63;
#pragma unroll
        for (int j = 0; j < 4; ++j) {
            int n = n0 + tx * 4 + j;
            int g = n >> 9, u = n & 511;
            gi[(((size_t)(ss * 512 + u)) * 3 + g) * 32 + bb] = acc[i][j] + (double)bih[n];
        }
    }
}

// ---------------------------------------------------------------------------
// K4 (round-23): round-16 base + gi load moved OFF wave0's poll-drain path.
//   Theory: consuming poll loads forces s_waitcnt vmcnt(0), which drains all
//   older VMEM ops — including the 3 gi HBM loads issued ~0.2us earlier at
//   the gates. Moving the gi load to iteration s (after phase-A staging,
//   ~1.2us before the gates that consume it) keeps wave0's next-step poll
//   free of young HBM loads. Gates read identical gi[s] values ->
//   bit-identical numerics. Everything else byte-identical to round-16.
// ---------------------------------------------------------------------------
__global__ __launch_bounds__(256, 1) void k4_gru(const double* __restrict__ gi,
                                                 const float* __restrict__ whh,
                                                 const float* __restrict__ bhh,
                                                 const int* __restrict__ length,
                                                 double* __restrict__ hstep,
                                                 float* __restrict__ outs,
                                                 short* __restrict__ A16) {
    __shared__ double hl[2112];               // group h: idx = e + (e>>7)*4
    __shared__ double part[2][4][16][13];     // [parity][wave][ul][gate*4+b], pad 13

    int t = threadIdx.x;
    int wv = t >> 6;
    int lane = t & 63;
    int bid = blockIdx.x;
    int g = bid & 7;          // group
    int beta = bid >> 3;      // block-in-group 0..31

    // matvec lane mapping: (ul, ks); wave wv covers k in [wv*128, wv*128+128)
    int ul = lane >> 2, ks = lane & 3;

    // ---- W_hh slice into registers: rows (gate*512 + beta*16 + ul),
    //      cols [wv*128 + ks*32, +32) = 8 float4 per gate ----
    const float* wbase = whh + ((size_t)(beta * 16 + ul)) * 512 + wv * 128 + ks * 32;
    float4 w0r[8], w1r[8], w2r[8];
#pragma unroll
    for (int c = 0; c < 8; ++c) {
        w0r[c] = *(const float4*)(wbase + c * 4);
        w1r[c] = *(const float4*)(wbase + 512 * 512 + c * 4);
        w2r[c] = *(const float4*)(wbase + 1024 * 512 + c * 4);
    }

    // ---- initial h (step 0), group-local 16KB (plain loads; pre-k4 data) ----
    const double* hg0 = hstep + (size_t)g * 2048;
    {
#pragma unroll
        for (int j = 0; j < 8; ++j) {
            int e = t + j * 256;
            hl[e + ((e >> 7) << 2)] = hg0[e];
        }
    }
    __syncthreads();

    // wave0 per-lane elementwise state: lane = (u2 0..15, b2 0..3)
    int u2 = lane >> 2, b2 = lane & 3;
    int u_g = beta * 16 + u2;      // global unit
    int b_g = g * 4 + b2;          // global batch
    double gr = 0.0, gz = 0.0, gn = 0.0, bhr_ = 0.0, bhz_ = 0.0, bhn_ = 0.0;
    double hv = 0.0;               // own h_prev in register
    int len = 0;
    if (wv == 0) {
        bhr_ = (double)bhh[u_g];
        bhz_ = (double)bhh[u_g + 512];
        bhn_ = (double)bhh[u_g + 1024];
        len = length[b_g];
        hv = hg0[u_g * 4 + b2];
        size_t gb = ((size_t)u_g * 3) * 32 + b_g;   // gi for step 0
        gr = gi[gb]; gz = gi[gb + 32]; gn = gi[gb + 64];
    }

    const double* hr = &hl[(wv * 128 + ks * 32) * 4 + ((wv * 4 + ks) << 2)];

    for (int s = 0; s < S_; ++s) {
        int par = s & 1;
        ull_ ta[4], tb[4];
        const ull_* src = (const ull_*)(hstep + (size_t)s * 16384 + (size_t)g * 2048)
                          + wv * 512;
        if (s > 0) {
            // ---- phase A: poll even-j chunks (coalesced lane-major) ----
            while (true) {
                bool ok = true;
#pragma unroll
                for (int j = 0; j < 4; ++j) {
                    ta[j] = __hip_atomic_load(&src[(2 * j) * 64 + lane],
                                              __ATOMIC_RELAXED, __HIP_MEMORY_SCOPE_AGENT);
                    ok = ok && (ta[j] != SENT);
                }
                if (__all(ok)) break;
                __builtin_amdgcn_s_sleep(1);
            }
            // first-try odd-j loads: in flight during stage + matvec A
#pragma unroll
            for (int j = 0; j < 4; ++j)
                tb[j] = __hip_atomic_load(&src[(2 * j + 1) * 64 + lane],
                                          __ATOMIC_RELAXED, __HIP_MEMORY_SCOPE_AGENT);
            asm volatile("" ::: "memory");
            {
                ull_* hlu = (ull_*)hl;
#pragma unroll
                for (int j = 0; j < 4; ++j) {
                    int e = wv * 512 + (2 * j) * 64 + lane;
                    hlu[e + ((e >> 7) << 2)] = ta[j];
                }
            }
            // gi load for THIS step's gates (wave0): issued ~1.2us before use
            // (matvec A+B+reduce), so wave0's NEXT-step poll has no young HBM
            // loads to drain at its vmcnt(0).
            if (wv == 0) {
                size_t gb = ((size_t)(s * 512 + u_g) * 3) * 32 + b_g;
                gr = gi[gb]; gz = gi[gb + 32]; gn = gi[gb + 64];
            }
        }

        double a0[4] = {0, 0, 0, 0}, a1[4] = {0, 0, 0, 0}, a2[4] = {0, 0, 0, 0};
        // ---- matvec phase A: c = 0..3 (k_local in even-j chunks) ----
#pragma unroll
        for (int c = 0; c < 4; ++c) {
            const double* hp = hr + c * 16;
            double2 hA0 = *(const double2*)(hp + 0),  hB0 = *(const double2*)(hp + 2);
            double2 hA1 = *(const double2*)(hp + 4),  hB1 = *(const double2*)(hp + 6);
            double2 hA2 = *(const double2*)(hp + 8),  hB2 = *(const double2*)(hp + 10);
            double2 hA3 = *(const double2*)(hp + 12), hB3 = *(const double2*)(hp + 14);
            float4 w0 = w0r[c], w1 = w1r[c], w2 = w2r[c];
            { double d0 = (double)w0.x, d1 = (double)w1.x, d2 = (double)w2.x;
              a0[0] += hA0.x * d0; a0[1] += hA0.y * d0; a0[2] += hB0.x * d0; a0[3] += hB0.y * d0;
              a1[0] += hA0.x * d1; a1[1] += hA0.y * d1; a1[2] += hB0.x * d1; a1[3] += hB0.y * d1;
              a2[0] += hA0.x * d2; a2[1] += hA0.y * d2; a2[2] += hB0.x * d2; a2[3] += hB0.y * d2; }
            { double d0 = (double)w0.y, d1 = (double)w1.y, d2 = (double)w2.y;
              a0[0] += hA1.x * d0; a0[1] += hA1.y * d0; a0[2] += hB1.x * d0; a0[3] += hB1.y * d0;
              a1[0] += hA1.x * d1; a1[1] += hA1.y * d1; a1[2] += hB1.x * d1; a1[3] += hB1.y * d1;
              a2[0] += hA1.x * d2; a2[1] += hA1.y * d2; a2[2] += hB1.x * d2; a2[3] += hB1.y * d2; }
            { double d0 = (double)w0.z, d1 = (double)w1.z, d2 = (double)w2.z;
              a0[0] += hA2.x * d0; a0[1] += hA2.y * d0; a0[2] += hB2.x * d0; a0[3] += hB2.y * d0;
              a1[0] += hA2.x * d1; a1[1] += hA2.y * d1; a1[2] += hB2.x * d1; a1[3] += hB2.y * d1;
              a2[0] += hA2.x * d2; a2[1] += hA2.y * d2; a2[2] += hB2.x * d2; a2[3] += hB2.y * d2; }
            { double d0 = (double)w0.w, d1 = (double)w1.w, d2 = (double)w2.w;
              a0[0] += hA3.x * d0; a0[1] += hA3.y * d0; a0[2] += hB3.x * d0; a0[3] += hB3.y * d0;
              a1[0] += hA3.x * d1; a1[1] += hA3.y * d1; a1[2] += hB3.x * d1; a1[3] += hB3.y * d1;
              a2[0] += hA3.x * d2; a2[1] += hA3.y * d2; a2[2] += hB3.x * d2; a2[3] += hB3.y * d2; }
        }

        if (s > 0) {
            // ---- phase B: verify/complete odd-j chunks, stage ----
            while (true) {
                bool ok = true;
#pragma unroll
                for (int j = 0; j < 4; ++j) ok = ok && (tb[j] != SENT);
                if (__all(ok)) break;
                __builtin_amdgcn_s_sleep(1);
#pragma unroll
                for (int j = 0; j < 4; ++j)
                    tb[j] = __hip_atomic_load(&src[(2 * j + 1) * 64 + lane],
                                              __ATOMIC_RELAXED, __HIP_MEMORY_SCOPE_AGENT);
            }
            asm volatile("" ::: "memory");
            {
                ull_* hlu = (ull_*)hl;
#pragma unroll
                for (int j = 0; j < 4; ++j) {
                    int e = wv * 512 + (2 * j + 1) * 64 + lane;
                    hlu[e + ((e >> 7) << 2)] = tb[j];
                }
            }
        }

        // ---- matvec phase B: c = 4..7 (k_local in odd-j chunks) ----
#pragma unroll
        for (int c = 4; c < 8; ++c) {
            const double* hp = hr + c * 16;
            double2 hA0 = *(const double2*)(hp + 0),  hB0 = *(const double2*)(hp + 2);
            double2 hA1 = *(const double2*)(hp + 4),  hB1 = *(const double2*)(hp + 6);
            double2 hA2 = *(const double2*)(hp + 8),  hB2 = *(const double2*)(hp + 10);
            double2 hA3 = *(const double2*)(hp + 12), hB3 = *(const double2*)(hp + 14);
            float4 w0 = w0r[c], w1 = w1r[c], w2 = w2r[c];
            { double d0 = (double)w0.x, d1 = (double)w1.x, d2 = (double)w2.x;
              a0[0] += hA0.x * d0; a0[1] += hA0.y * d0; a0[2] += hB0.x * d0; a0[3] += hB0.y * d0;
              a1[0] += hA0.x * d1; a1[1] += hA0.y * d1; a1[2] += hB0.x * d1; a1[3] += hB0.y * d1;
              a2[0] += hA0.x * d2; a2[1] += hA0.y * d2; a2[2] += hB0.x * d2; a2[3] += hB0.y * d2; }
            { double d0 = (double)w0.y, d1 = (double)w1.y, d2 = (double)w2.y;
              a0[0] += hA1.x * d0; a0[1] += hA1.y * d0; a0[2] += hB1.x * d0; a0[3] += hB1.y * d0;
              a1[0] += hA1.x * d1; a1[1] += hA1.y * d1; a1[2] += hB1.x * d1; a1[3] += hB1.y * d1;
              a2[0] += hA1.x * d2; a2[1] += hA1.y * d2; a2[2] += hB1.x * d2; a2[3] += hB1.y * d2; }
            { double d0 = (double)w0.z, d1 = (double)w1.z, d2 = (double)w2.z;
              a0[0] += hA2.x * d0; a0[1] += hA2.y * d0; a0[2] += hB2.x * d0; a0[3] += hB2.y * d0;
              a1[0] += hA2.x * d1; a1[1] += hA2.y * d1; a1[2] += hB2.x * d1; a1[3] += hB2.y * d1;
              a2[0] += hA2.x * d2; a2[1] += hA2.y * d2; a2[2] += hB2.x * d2; a2[3] += hB2.y * d2; }
            { double d0 = (double)w0.w, d1 = (double)w1.w, d2 = (double)w2.w;
              a0[0] += hA3.x * d0; a0[1] += hA3.y * d0; a0[2] += hB3.x * d0; a0[3] += hB3.y * d0;
              a1[0] += hA3.x * d1; a1[1] += hA3.y * d1; a1[2] += hB3.x * d1; a1[3] += hB3.y * d1;
              a2[0] += hA3.x * d2; a2[1] += hA3.y * d2; a2[2] += hB3.x * d2; a2[3] += hB3.y * d2; }
        }

        // reduce over ks (lanes xor 1, 2)
#pragma unroll
        for (int b = 0; b < 4; ++b) {
            a0[b] += __shfl_xor(a0[b], 1); a0[b] += __shfl_xor(a0[b], 2);
            a1[b] += __shfl_xor(a1[b], 1); a1[b] += __shfl_xor(a1[b], 2);
            a2[b] += __shfl_xor(a2[b], 1); a2[b] += __shfl_xor(a2[b], 2);
        }
        if (ks == 0) {
#pragma unroll
            for (int b = 0; b < 4; ++b) {
                part[par][wv][ul][0 * 4 + b] = a0[b];
                part[par][wv][ul][1 * 4 + b] = a1[b];
                part[par][wv][ul][2 * 4 + b] = a2[b];
            }
        }
        __syncthreads();   // S1 (only barrier per step): partials visible

        if (wv == 0) {
            double s0 = part[par][0][u2][0 * 4 + b2] + part[par][1][u2][0 * 4 + b2]
                      + part[par][2][u2][0 * 4 + b2] + part[par][3][u2][0 * 4 + b2];
            double s1 = part[par][0][u2][1 * 4 + b2] + part[par][1][u2][1 * 4 + b2]
                      + part[par][2][u2][1 * 4 + b2] + part[par][3][u2][1 * 4 + b2];
            double s2 = part[par][0][u2][2 * 4 + b2] + part[par][1][u2][2 * 4 + b2]
                      + part[par][2][u2][2 * 4 + b2] + part[par][3][u2][2 * 4 + b2];
            double r  = 1.0 / (1.0 + exp(-(gr + s0 + bhr_)));
            double zt = 1.0 / (1.0 + exp(-(gz + s1 + bhz_)));
            double n  = tanh(gn + r * (s2 + bhn_));
            double hn_ = (1.0 - zt) * n + zt * hv;
            hv = hn_;
            if (s < S_ - 1) {
                // publish to write-once step buffer; the data IS the flag
                ull_* hdst = (ull_*)(hstep + (size_t)(s + 1) * 16384 + (size_t)g * 2048);
                // (beta*16+u2)*4 + b2 == beta*64 + lane -> fully coalesced 512B store
                __hip_atomic_store(&hdst[beta * 64 + lane],
                                   __builtin_bit_cast(ull_, hn_),
                                   __ATOMIC_RELAXED, __HIP_MEMORY_SCOPE_AGENT);
            }
            float ov = (s < len) ? (float)hn_ : 0.0f;
            size_t oidx = (size_t)(b_g * 64 + s) * H_ + u_g;
            outs[oidx] = ov;
            {   // fused bf16 conversion (was k_prep2's A-half)
                unsigned u = __builtin_bit_cast(unsigned, ov);
                A16[oidx] = (short)((u + 0x7FFFu + ((u >> 16) & 1u)) >> 16);
            }
        }
    }
}

// ---------------------------------------------------------------------------
// bf16 helpers + prep kernel (W16 only): blocks [0,5000) convert W_out.
// ---------------------------------------------------------------------------
__device__ __forceinline__ unsigned short f2b_(float x) {
    unsigned u = __builtin_bit_cast(unsigned, x);
    return (unsigned short)((u + 0x7FFFu + ((u >> 16) & 1u)) >> 16);   // RNE
}
__device__ __forceinline__ short8v pack8_(float4 a, float4 b) {
    short8v r;
    r[0] = (short)f2b_(a.x); r[1] = (short)f2b_(a.y);
    r[2] = (short)f2b_(a.z); r[3] = (short)f2b_(a.w);
    r[4] = (short)f2b_(b.x); r[5] = (short)f2b_(b.y);
    r[6] = (short)f2b_(b.z); r[7] = (short)f2b_(b.w);
    return r;
}
__global__ __launch_bounds__(256) void k_prep2(const float* __restrict__ Wsrc,
                                               short* __restrict__ W16) {
    int i = blockIdx.x * 256 + threadIdx.x;  // < 1,280,000
    float4 a = *(const float4*)&Wsrc[(size_t)i * 8];
    float4 b = *(const float4*)&Wsrc[(size_t)i * 8 + 4];
    *(short8v*)&W16[(size_t)i * 8] = pack8_(a, b);
}

// ---------------------------------------------------------------------------
// K5 (round-16 PROVEN): p = sigmoid(A16 @ W16^T + b_out), bf16 MFMA. BK=64.
//     128x128 tile, 4 waves (2x2 of 64x64), LDS stride 72. Grid 2512.
//     [R21 note: 128x256 retile measured +38us WORSE — de-coalesced 1-thread-
//      per-row B staging. Do not retry without per-kernel timing.]
// ---------------------------------------------------------------------------
#define LDK5 72
__global__ __launch_bounds__(256, 2) void k5_mfma(const short* __restrict__ A16,  // 2048x512 bf16
                                                  const short* __restrict__ W16,  // 20000x512 bf16
                                                  const float* __restrict__ bo,
                                                  float* __restrict__ pOut) {
    __shared__ short As[128 * LDK5];   // 18.4KB
    __shared__ short Bs[128 * LDK5];
    int t = threadIdx.x;
    int bid = blockIdx.x;                       // 0..2511
    int swz = (bid & 7) * 314 + (bid >> 3);     // XCD swizzle (bijective, 2512=8*314)
    int m0 = (swz & 15) * 128;
    int n0 = (swz >> 4) * 128;
    int lane = t & 63, wv = t >> 6;
    int wr = wv >> 1, wc = wv & 1;              // wave -> 64x64 quadrant
    int ml = t >> 1;                            // 0..127 (staging row)
    int kl = (t & 1) * 32;                      // 0 or 32 (staging k-offset)

    const short* Arow = A16 + (size_t)(m0 + ml) * H_ + kl;
    int vrow = n0 + ml;
    bool vok = vrow < V_;
    const short* Wrow = W16 + (size_t)(vok ? vrow : 0) * H_ + kl;
    short8v zz = (short8v){0, 0, 0, 0, 0, 0, 0, 0};

    f32x4 acc[4][4];
#pragma unroll
    for (int i = 0; i < 4; ++i)
#pragma unroll
        for (int j = 0; j < 4; ++j) acc[i][j] = (f32x4){0.f, 0.f, 0.f, 0.f};

    int ko = lane >> 4;       // 0..3 (k-group of 8)
    int rr = lane & 15;       // fragment row/col

    for (int kt = 0; kt < H_; kt += 64) {
        short8v a0 = *(const short8v*)(Arow + kt);
        short8v a1 = *(const short8v*)(Arow + kt + 8);
        short8v a2 = *(const short8v*)(Arow + kt + 16);
        short8v a3 = *(const short8v*)(Arow + kt + 24);
        short8v b0 = vok ? *(const short8v*)(Wrow + kt) : zz;
        short8v b1 = vok ? *(const short8v*)(Wrow + kt + 8) : zz;
        short8v b2 = vok ? *(const short8v*)(Wrow + kt + 16) : zz;
        short8v b3 = vok ? *(const short8v*)(Wrow + kt + 24) : zz;
        *(short8v*)&As[ml * LDK5 + kl]      = a0;
        *(short8v*)&As[ml * LDK5 + kl + 8]  = a1;
        *(short8v*)&As[ml * LDK5 + kl + 16] = a2;
        *(short8v*)&As[ml * LDK5 + kl + 24] = a3;
        *(short8v*)&Bs[ml * LDK5 + kl]      = b0;
        *(short8v*)&Bs[ml * LDK5 + kl + 8]  = b1;
        *(short8v*)&Bs[ml * LDK5 + kl + 16] = b2;
        *(short8v*)&Bs[ml * LDK5 + kl + 24] = b3;
        __syncthreads();

#pragma unroll
        for (int kh = 0; kh < 2; ++kh) {
            short8v af[4], bf[4];
#pragma unroll
            for (int i = 0; i < 4; ++i)
                af[i] = *(const short8v*)&As[(wr * 64 + i * 16 + rr) * LDK5 + kh * 32 + ko * 8];
#pragma unroll
            for (int j = 0; j < 4; ++j)
                bf[j] = *(const short8v*)&Bs[(wc * 64 + j * 16 + rr) * LDK5 + kh * 32 + ko * 8];
#pragma unroll
            for (int i = 0; i < 4; ++i)
#pragma unroll
                for (int j = 0; j < 4; ++j)
                    acc[i][j] = __builtin_amdgcn_mfma_f32_16x16x32_bf16(af[i], bf[j], acc[i][j], 0, 0, 0);
        }
        __syncthreads();
    }

    int cr4 = (lane >> 4) * 4;
    float bov[4];
#pragma unroll
    for (int j = 0; j < 4; ++j) {
        int v = n0 + wc * 64 + j * 16 + rr;
        bov[j] = (v < V_) ? bo[v] : 0.f;
    }
#pragma unroll
    for (int i = 0; i < 4; ++i) {
#pragma unroll
        for (int j = 0; j < 4; ++j) {
            int v = n0 + wc * 64 + j * 16 + rr;
            if (v < V_) {
#pragma unroll
                for (int r = 0; r < 4; ++r) {
                    int m = m0 + wr * 64 + i * 16 + cr4 + r;
                    float x = acc[i][j][r] + bov[j];
                    pOut[(size_t)m * V_ + v] = 1.0f / (1.0f + expf(-x));
                }
            }
        }
    }
}

// ---------------------------------------------------------------------------
// K7a (round-20 PROVEN): per-wave top-32, sorted-top-4 maintenance.
// ---------------------------------------------------------------------------
__global__ __launch_bounds__(512) void k7a_cand(const float* __restrict__ pOut,
                                                float* __restrict__ candV,
                                                int* __restrict__ candI) {
    int row = blockIdx.x;
    int t = threadIdx.x;
    int wv = t >> 6;          // chunk 0..7 (2500 cols each)
    int lane = t & 63;
    const float* rowp = pOut + (size_t)row * V_ + wv * 2500;

    float rv[40];
#pragma unroll
    for (int q4 = 0; q4 < 10; ++q4) {
        int base = q4 * 256 + lane * 4;
        float4 v4 = *(const float4*)(rowp + base);   // tails stay inside d_out; masked below
        float vv[4] = {v4.x, v4.y, v4.z, v4.w};
#pragma unroll
        for (int c = 0; c < 4; ++c) {
            int li = base + c;
            int col = wv * 2500 + li;
            bool ok = (li < 2500) && (col >= 3);
            rv[q4 * 4 + c] = ok ? vv[c] : NEG7;
        }
    }

    // sorted top-4 (v desc, q asc): stable strict-> insertion in q order
    float v0 = NEG7, v1 = NEG7, v2 = NEG7, v3 = NEG7;
    int   i0 = 0,    i1 = 0,    i2 = 0,    i3 = 0;
#pragma unroll
    for (int q = 0; q < 40; ++q) {
        float v = rv[q];
        if (v > v3) {
            if (v > v1) {
                if (v > v0) { v3 = v2; i3 = i2; v2 = v1; i2 = i1; v1 = v0; i1 = i0; v0 = v; i0 = q; }
                else        { v3 = v2; i3 = i2; v2 = v1; i2 = i1; v1 = v; i1 = q; }
            } else {
                if (v > v2) { v3 = v2; i3 = i2; v2 = v; i2 = q; }
                else        { v3 = v; i3 = q; }
            }
        }
    }

    ull_ used = 0;
    int pops = 0;
    int myidx = wv * 2500 + (i0 >> 2) * 256 + lane * 4 + (i0 & 3);

    float keepv = NEG7; int keepi = 0;
#pragma unroll 1
    for (int r = 0; r < 32; ++r) {
        float bv = v0; int bi = myidx;
#pragma unroll
        for (int m = 1; m < 64; m <<= 1) {
            float ov = __shfl_xor(bv, m);
            int   oi = __shfl_xor(bi, m);
            if (ov > bv || (ov == bv && oi < bi)) { bv = ov; bi = oi; }
        }
        if (lane == r) { keepv = bv; keepi = bi; }
        if (myidx == bi) {           // this lane won (idx unique -> exactly one)
            used |= (1ull << i0);
            v0 = v1; i0 = i1; v1 = v2; i1 = i2; v2 = v3; i2 = i3; v3 = NEG7; i3 = 0;
            if (++pops == 4) {       // list exhausted: rare rebuild (excl. used)
                pops = 0;
                v0 = v1 = v2 = v3 = NEG7; i0 = i1 = i2 = i3 = 0;
#pragma unroll
                for (int q = 0; q < 40; ++q) {
                    float v = ((used >> q) & 1ull) ? NEG7 : rv[q];
                    if (v > v3) {
                        if (v > v1) {
                            if (v > v0) { v3 = v2; i3 = i2; v2 = v1; i2 = i1; v1 = v0; i1 = i0; v0 = v; i0 = q; }
                            else        { v3 = v2; i3 = i2; v2 = v1; i2 = i1; v1 = v; i1 = q; }
                        } else {
                            if (v > v2) { v3 = v2; i3 = i2; v2 = v; i2 = q; }
                            else        { v3 = v; i3 = q; }
                        }
                    }
                }
            }
            myidx = wv * 2500 + (i0 >> 2) * 256 + lane * 4 + (i0 & 3);
        }
    }
    if (lane < 32) {
        size_t o = ((size_t)row * 8 + wv) * 32 + lane;
        candV[o] = keepv;
        candI[o] = keepi;
    }
}

// ---------------------------------------------------------------------------
// K7b (round-16 PROVEN): merge 256 candidates -> top-64 (stable); f64
//     rescore; final top-30 by (rescored desc, idx asc); m_output.
// ---------------------------------------------------------------------------
__global__ __launch_bounds__(256) void k7b_final(const float* __restrict__ candV,
                                                 const int* __restrict__ candI,
                                                 const float* __restrict__ outs,
                                                 const float* __restrict__ W,
                                                 const float* __restrict__ bo,
                                                 float* __restrict__ mOut,
                                                 float* __restrict__ sOut) {
    __shared__ float selv[64];
    __shared__ int   seli[64];
    __shared__ float resv[64];
    __shared__ float redm[4];
    __shared__ __align__(16) float orow[H_];

    int row = blockIdx.x;
    int t = threadIdx.x;
    int lane = t & 63, wid = t >> 6;

    if (wid != 0) {
        for (int i = t - 64; i < H_; i += 192)
            orow[i] = outs[(size_t)row * H_ + i];
    } else {
        float cv[4]; int ci[4];
#pragma unroll
        for (int q = 0; q < 4; ++q) {
            size_t o = (size_t)row * 256 + q * 64 + lane;
            cv[q] = candV[o];
            ci[q] = candI[o];
        }
        float lv = cv[0]; int lix = ci[0]; int ls = 0;
#pragma unroll
        for (int q = 1; q < 4; ++q)
            if (cv[q] > lv || (cv[q] == lv && ci[q] < lix)) { lv = cv[q]; lix = ci[q]; ls = q; }

#pragma unroll 1
        for (int r = 0; r < 64; ++r) {
            float bv = lv; int bi = lix;
#pragma unroll
            for (int m = 1; m < 64; m <<= 1) {
                float ov = __shfl_xor(bv, m);
                int   oi = __shfl_xor(bi, m);
                if (ov > bv || (ov == bv && oi < bi)) { bv = ov; bi = oi; }
            }
            if (lane == r) { selv[r] = bv; seli[r] = bi; }
            if (lix == bi) {
#pragma unroll
                for (int q = 0; q < 4; ++q) cv[q] = (ls == q) ? NEG7 : cv[q];
                lv = cv[0]; lix = ci[0]; ls = 0;
#pragma unroll
                for (int q = 1; q < 4; ++q)
                    if (cv[q] > lv || (cv[q] == lv && ci[q] < lix)) { lv = cv[q]; lix = ci[q]; ls = q; }
            }
        }
    }
    __syncthreads();

    {
        float ms = fabsf(orow[t]) + fabsf(orow[t + 256]);
#pragma unroll
        for (int m = 1; m < 64; m <<= 1) ms += __shfl_xor(ms, m);
        if (lane == 0) redm[wid] = ms;
    }

    {
        int c = t >> 2, q = t & 3;
        int gidx = seli[c];
        const float4* w4 = (const float4*)(W + (size_t)gidx * H_);
        const float4* o4 = (const float4*)orow;
        double acc = 0.0;
#pragma unroll 8
        for (int i2 = 0; i2 < 32; ++i2) {
            float4 wv4 = w4[i2 * 4 + q];
            float4 ov4 = o4[i2 * 4 + q];
            acc += (double)wv4.x * (double)ov4.x + (double)wv4.y * (double)ov4.y
                 + (double)wv4.z * (double)ov4.z + (double)wv4.w * (double)ov4.w;
        }
        acc += __shfl_xor(acc, 1);
        acc += __shfl_xor(acc, 2);
        if (q == 0) resv[c] = (float)(acc + (double)bo[gidx]);
    }
    __syncthreads();

    if (t == 0)
        mOut[row] = (redm[0] + redm[1] + redm[2] + redm[3] > 0.f) ? 1.f : 0.f;

    if (t < 64) {
        float v = resv[t];
        int idx = seli[t];
#pragma unroll 1
        for (int r = 0; r < MV_; ++r) {
            float bv = v; int bi = idx;
#pragma unroll
            for (int m = 1; m < 64; m <<= 1) {
                float ov = __shfl_xor(bv, m);
                int   oi = __shfl_xor(bi, m);
                if (ov > bv || (ov == bv && oi < bi)) { bv = ov; bi = oi; }
            }
            if (t == 0)
                sOut[(size_t)row * MV_ + r] = (bv <= 0.0f) ? 0.0f : (float)bi;
            if (idx == bi) v = NEG7;
        }
    }
}

// ---------------------------------------------------------------------------
extern "C" void kernel_launch(void* const* d_in, const int* in_sizes, int n_in,
                              void* d_out, int out_size, void* d_ws, size_t ws_size,
                              hipStream_t stream) {
    const float* z      = (const float*)d_in[0];
    const int*   seq    = (const int*)d_in[1];
    const int*   length = (const int*)d_in[2];
    const float* Ew     = (const float*)d_in[3];
    const float* W_l2h  = (const float*)d_in[4];
    const float* b_l2h  = (const float*)d_in[5];
    const float* W_ih   = (const float*)d_in[6];
    const float* W_hh   = (const float*)d_in[7];
    const float* b_ih   = (const float*)d_in[8];
    const float* b_hh   = (const float*)d_in[9];
    const float* W_out  = (const float*)d_in[10];
    const float* b_out  = (const float*)d_in[11];

    float* out = (float*)d_out;

    double* emb_d = (double*)d_ws;               // 2048*256 f64 (A16 overlay after k3)
    double* gi_d  = emb_d + 524288;              // 2048*1536 f64 (W16 overlay after k4)
    double* hstep = gi_d + 3145728;              // 64 x 16384 f64 per-step h buffers (8MB)
    float*  outs  = (float*)(hstep + 1048576);   // 2048*512 f32
    float*  candV = outs + 1048576;              // 2048*256 f32
    int*    candI = (int*)(candV + (size_t)BS_ * 256);   // 2048*256 i32
    short*  A16   = (short*)emb_d;               // 2048*512 bf16 (emb dead after k3)
    short*  W16   = (short*)gi_d;                // 20000*512 bf16 (gi dead after k4)

    float* pOut = out;                           // 2048*20000
    float* sOut = out + (size_t)BS_ * V_;        // 2048*30
    float* mOut = sOut + (size_t)BS_ * MV_;      // 2048

    k12<<<BS_ + 64 + 1008, 256, 0, stream>>>(seq, Ew, z, W_l2h, b_l2h, emb_d, hstep);
    k3_gi<<<dim3(24, 32), 256, 0, stream>>>(emb_d, W_ih, b_ih, gi_d);
    k4_gru<<<NB4, 256, 0, stream>>>(gi_d, W_hh, b_hh, length, hstep, outs, A16);
    k_prep2<<<5000, 256, 0, stream>>>(W_out, W16);
    k5_mfma<<<2512, 256, 0, stream>>>(A16, W16, b_out, pOut);
    k7a_cand<<<BS_, 512, 0, stream>>>(pOut, candV, candI);
    k7b_final<<<BS_, 256, 0, stream>>>(candV, candI, outs, W_out, b_out, mOut, sOut);
}